// Round 4
// baseline (909.771 us; speedup 1.0000x reference)
//
#include <hip/hip_runtime.h>
#include <hip/hip_bf16.h>
#include <math.h>

namespace {

constexpr int Bb = 8, Ll = 1024, Dd = 768, Hh = 12, DHh = 64;
constexpr int DDm = Dd * Dd;
constexpr float MAXN = 1.0f - 1e-5f;
constexpr float EPSf = 1e-15f;

typedef __attribute__((ext_vector_type(8))) short short8;
typedef __attribute__((ext_vector_type(4))) float f32x4;

__device__ __forceinline__ float wred64(float v) {
#pragma unroll
  for (int m = 32; m >= 1; m >>= 1) v += __shfl_xor(v, m, 64);
  return v;
}

__device__ __forceinline__ float artanh_(float x) {
  return 0.5f * logf((1.0f + x) / (1.0f - x));
}

__device__ __forceinline__ void bsplit(float x, unsigned short& h,
                                       unsigned short& l) {
  __hip_bfloat16 hb = __float2bfloat16(x);
  const float hf = __bfloat162float(hb);
  __hip_bfloat16 lb = __float2bfloat16(x - hf);
  h = *(unsigned short*)&hb;
  l = *(unsigned short*)&lb;
}

// e = exp(-scale * 2*artanh(t)) = ((1-t)/(1+t))^scale ; fast path scale==1
__device__ __forceinline__ float score_e(float qk, float q2v, float k2v,
                                         float scale, bool sone) {
  const float diff2 = fmaxf(q2v + k2v - 2.0f * qk, 0.0f);
  const float den = fmaxf(1.0f - 2.0f * qk + q2v * k2v, EPSf);
  const float r = diff2 * __builtin_amdgcn_rcpf(den);
  const float t = fminf(sqrtf(fmaxf(r, 0.0f)), MAXN);
  const float p = (1.0f - t) * __builtin_amdgcn_rcpf(1.0f + t);
  return sone ? p : expf(scale * logf(p));
}

// ---------------------------------------------------------------------------
// Split fp32 -> bf16 hi + bf16 lo.
// ---------------------------------------------------------------------------
__global__ __launch_bounds__(256) void k_cvt(const float* __restrict__ in,
                                             unsigned short* __restrict__ hi,
                                             unsigned short* __restrict__ lo,
                                             int n4) {
  const int i = blockIdx.x * 256 + threadIdx.x;
  if (i >= n4) return;
  float4 v = ((const float4*)in)[i];
  float xs[4] = {v.x, v.y, v.z, v.w};
  unsigned short hs[4], ls[4];
#pragma unroll
  for (int j = 0; j < 4; j++) bsplit(xs[j], hs[j], ls[j]);
  ((ushort4*)hi)[i] = make_ushort4(hs[0], hs[1], hs[2], hs[3]);
  ((ushort4*)lo)[i] = make_ushort4(ls[0], ls[1], ls[2], ls[3]);
}

// ---------------------------------------------------------------------------
// bf16-split MFMA GEMM: C = A @ W^T (~fp32 precision).
// ---------------------------------------------------------------------------
__global__ __launch_bounds__(256) void k_gemm_bf16s(
    const unsigned short* __restrict__ Ahi, const unsigned short* __restrict__ Alo,
    const unsigned short* __restrict__ Whi, const unsigned short* __restrict__ Wlo,
    float* __restrict__ C) {
  constexpr int K = Dd, N = Dd;
  const int z = blockIdx.z;
  const unsigned short* Bh = Whi + (size_t)z * DDm;
  const unsigned short* Bl = Wlo + (size_t)z * DDm;
  float* Cz = C + (size_t)z * 8192 * N;
  __shared__ __align__(16) unsigned short sAh[128 * 32];
  __shared__ __align__(16) unsigned short sAl[128 * 32];
  __shared__ __align__(16) unsigned short sBh[128 * 32];
  __shared__ __align__(16) unsigned short sBl[128 * 32];
  const int t = threadIdx.x;
  const int l = t & 63, wid = t >> 6;
  const int wr = wid >> 1, wc = wid & 1;
  const int m0 = blockIdx.y * 128, n0 = blockIdx.x * 128;

  const int r0 = t >> 2, kf0 = t & 3;
  const int r1 = (t + 256) >> 2, kf1 = (t + 256) & 3;
  const int sw0 = r0 * 32 + ((kf0 ^ ((r0 >> 1) & 3)) << 3);
  const int sw1 = r1 * 32 + ((kf1 ^ ((r1 >> 1) & 3)) << 3);
  const size_t ga0 = (size_t)(m0 + r0) * K + kf0 * 8;
  const size_t ga1 = (size_t)(m0 + r1) * K + kf1 * 8;
  const size_t gb0 = (size_t)(n0 + r0) * K + kf0 * 8;
  const size_t gb1 = (size_t)(n0 + r1) * K + kf1 * 8;

  const int lar = l & 15, lkf = l >> 4;

  f32x4 acc[4][4] = {};

  for (int k0 = 0; k0 < K; k0 += 32) {
    const short8 vah0 = *(const short8*)&Ahi[ga0 + k0];
    const short8 vah1 = *(const short8*)&Ahi[ga1 + k0];
    const short8 val0 = *(const short8*)&Alo[ga0 + k0];
    const short8 val1 = *(const short8*)&Alo[ga1 + k0];
    const short8 vbh0 = *(const short8*)&Bh[gb0 + k0];
    const short8 vbh1 = *(const short8*)&Bh[gb1 + k0];
    const short8 vbl0 = *(const short8*)&Bl[gb0 + k0];
    const short8 vbl1 = *(const short8*)&Bl[gb1 + k0];
    __syncthreads();
    *(short8*)&sAh[sw0] = vah0;
    *(short8*)&sAh[sw1] = vah1;
    *(short8*)&sAl[sw0] = val0;
    *(short8*)&sAl[sw1] = val1;
    *(short8*)&sBh[sw0] = vbh0;
    *(short8*)&sBh[sw1] = vbh1;
    *(short8*)&sBl[sw0] = vbl0;
    *(short8*)&sBl[sw1] = vbl1;
    __syncthreads();

    short8 ah[4], al[4], bh[4], bl[4];
#pragma unroll
    for (int f = 0; f < 4; f++) {
      const int ra = wr * 64 + f * 16 + lar;
      const int ia = ra * 32 + ((lkf ^ ((ra >> 1) & 3)) << 3);
      ah[f] = *(const short8*)&sAh[ia];
      al[f] = *(const short8*)&sAl[ia];
      const int rb = wc * 64 + f * 16 + lar;
      const int ib = rb * 32 + ((lkf ^ ((rb >> 1) & 3)) << 3);
      bh[f] = *(const short8*)&sBh[ib];
      bl[f] = *(const short8*)&sBl[ib];
    }
#pragma unroll
    for (int i = 0; i < 4; i++)
#pragma unroll
      for (int j = 0; j < 4; j++) {
        acc[i][j] = __builtin_amdgcn_mfma_f32_16x16x32_bf16(ah[i], bh[j],
                                                            acc[i][j], 0, 0, 0);
        acc[i][j] = __builtin_amdgcn_mfma_f32_16x16x32_bf16(ah[i], bl[j],
                                                            acc[i][j], 0, 0, 0);
        acc[i][j] = __builtin_amdgcn_mfma_f32_16x16x32_bf16(al[i], bh[j],
                                                            acc[i][j], 0, 0, 0);
      }
  }

#pragma unroll
  for (int i = 0; i < 4; i++)
#pragma unroll
    for (int j = 0; j < 4; j++) {
      const int row = m0 + wr * 64 + i * 16 + (l >> 4) * 4;
      const int col = n0 + wc * 64 + j * 16 + (l & 15);
      const f32x4 v = acc[i][j];
#pragma unroll
      for (int q = 0; q < 4; q++) Cz[(size_t)(row + q) * N + col] = v[q];
    }
}

// ---------------------------------------------------------------------------
// Per-row transform; emits q/k/(lam*v) as bf16 hi/lo + per-head stats.
// ---------------------------------------------------------------------------
__global__ __launch_bounds__(768) void k_qkv_transform(
    const float* __restrict__ x,
    const float* __restrict__ mq, const float* __restrict__ mk,
    const float* __restrict__ mv,
    unsigned short* __restrict__ qhh, unsigned short* __restrict__ qhl,
    unsigned short* __restrict__ khh, unsigned short* __restrict__ khl,
    unsigned short* __restrict__ vhh, unsigned short* __restrict__ vhl_,
    float* __restrict__ q2n, float* __restrict__ k2n,
    float* __restrict__ lam1, float beta_ratio) {
  const int t = threadIdx.x;
  const int row = blockIdx.x;  // b*L + l
  const int b = row >> 10, l = row & 1023;
  const int w = t >> 6, lane = t & 63;
  __shared__ float red[12];

  const float xe = x[(size_t)row * Dd + t];
  float s = wred64(xe * xe);
  if (lane == 0) red[w] = s;
  __syncthreads();
  float xn2 = 0.0f;
#pragma unroll
  for (int i = 0; i < 12; i++) xn2 += red[i];
  const float xn = sqrtf(fmaxf(xn2, EPSf * EPSf));
  const float arx = artanh_(fminf(xn, MAXN));

  const float* mptr[3] = {mq, mk, mv};
#pragma unroll
  for (int mi = 0; mi < 3; mi++) {
    const float me = mptr[mi][(size_t)row * Dd + t];
    __syncthreads();
    float s2 = wred64(me * me);
    if (lane == 0) red[w] = s2;
    __syncthreads();
    float mn2 = 0.0f;
#pragma unroll
    for (int i = 0; i < 12; i++) mn2 += red[i];
    const float mxn = sqrtf(fmaxf(mn2, EPSf * EPSf));
    const float pn = tanhf(mxn / xn * arx);
    const float c1 = pn / mxn * fminf(1.0f, MAXN / fmaxf(pn, EPSf));
    const float nn = fmaxf(fminf(pn, MAXN), EPSf);
    const float c2 = artanh_(nn) / nn;
    const float ve = c2 * c1 * me * beta_ratio;
    const float hs = wred64(ve * ve);
    const float hn = sqrtf(fmaxf(hs, EPSf * EPSf));
    const float th = tanhf(hn);
    const float oe = th / hn * ve;
    const size_t hidx = (size_t)(b * Hh + w) * Ll + l;
    const size_t oidx = hidx * DHh + lane;
    unsigned short hu, lu;
    if (mi == 0) {
      bsplit(oe, hu, lu);
      qhh[oidx] = hu; qhl[oidx] = lu;
      if (lane == 0) q2n[hidx] = th * th;
    } else if (mi == 1) {
      bsplit(oe, hu, lu);
      khh[oidx] = hu; khl[oidx] = lu;
      if (lane == 0) k2n[hidx] = th * th;
    } else {
      const float lam = 2.0f / fmaxf(1.0f - th * th, EPSf);
      bsplit(lam * oe, hu, lu);
      vhh[oidx] = hu; vhl_[oidx] = lu;
      if (lane == 0) lam1[hidx] = lam - 1.0f;
    }
  }
}

// ---------------------------------------------------------------------------
// Transpose lam*v per head: [k][d] -> [d][k] (bf16 hi/lo).
// ---------------------------------------------------------------------------
__global__ __launch_bounds__(256) void k_vt(const unsigned short* __restrict__ vh,
                                            const unsigned short* __restrict__ vl,
                                            unsigned short* __restrict__ th,
                                            unsigned short* __restrict__ tl) {
  __shared__ __align__(16) unsigned short sh[64 * 72];
  __shared__ __align__(16) unsigned short sl[64 * 72];
  const int t = threadIdx.x;
  const int bh = blockIdx.y, c = blockIdx.x;
  const size_t ibase = ((size_t)bh * Ll + c * 64) * DHh;
#pragma unroll
  for (int u = 0; u < 2; u++) {
    const int ch = t + u * 256, r = ch >> 3, f = ch & 7;
    *(short8*)&sh[r * 72 + f * 8] = *(const short8*)&vh[ibase + r * DHh + f * 8];
    *(short8*)&sl[r * 72 + f * 8] = *(const short8*)&vl[ibase + r * DHh + f * 8];
  }
  __syncthreads();
#pragma unroll
  for (int u = 0; u < 2; u++) {
    const int ch = t + u * 256, d = ch >> 3, kb = ch & 7;
    short8 oh, ol;
#pragma unroll
    for (int i = 0; i < 8; i++) {
      oh[i] = (short)sh[(kb * 8 + i) * 72 + d];
      ol[i] = (short)sl[(kb * 8 + i) * 72 + d];
    }
    const size_t ob = ((size_t)bh * DHh + d) * Ll + c * 64 + kb * 8;
    *(short8*)&th[ob] = oh;
    *(short8*)&tl[ob] = ol;
  }
}

// ---------------------------------------------------------------------------
// Fused attention: single pass. Grid (64, B*H), 512 threads (8 waves).
// Each block: 16 q-rows; wave w owns k in [w*128, w*128+128).
// Unnormalized e kept in registers (32/thread); PV uses unnormalized weights
// (Mobius-midpoint ratio is scale-invariant); one cross-wave reduce gives
// rowsums (for the attn write) and pv/den totals (for the midpoint).
// ---------------------------------------------------------------------------
__global__ __launch_bounds__(512) void k_attn_fused(
    const unsigned short* __restrict__ qhh, const unsigned short* __restrict__ qhl,
    const unsigned short* __restrict__ khh, const unsigned short* __restrict__ khl,
    const unsigned short* __restrict__ vth, const unsigned short* __restrict__ vtl,
    const float* __restrict__ q2n, const float* __restrict__ k2n,
    const float* __restrict__ lam1, const float* __restrict__ scale_p,
    float* __restrict__ attn, float* __restrict__ yh) {
  __shared__ __align__(16) unsigned short wlds[8][16 * 72];
  __shared__ float rsred[8][16];
  __shared__ float pvred[7][64][21];  // 16 pv + 4 dacc (stride 21: no conflict)
  const int t = threadIdx.x, l = t & 63, w = t >> 6;
  const int lr = l & 15, lg = l >> 4;
  const int bh = blockIdx.y, q0 = blockIdx.x * 16;
  const size_t hbase = (size_t)bh * Ll;
  const float scale = scale_p[0];
  const bool sone = (scale == 1.0f);
  const int k0w = w * 128;

  // Q fragments (A): lane row = lr, k-slice = lg*8 within s*32.
  short8 aqh[2], aql[2];
#pragma unroll
  for (int s = 0; s < 2; s++) {
    const size_t off = (hbase + q0 + lr) * (size_t)DHh + s * 32 + lg * 8;
    aqh[s] = *(const short8*)&qhh[off];
    aql[s] = *(const short8*)&qhl[off];
  }
  float q2r[4];
#pragma unroll
  for (int r = 0; r < 4; r++) q2r[r] = q2n[hbase + q0 + lg * 4 + r];

  float E[32];
  float rs[4] = {0.0f, 0.0f, 0.0f, 0.0f};
  float dacc[4] = {0.0f, 0.0f, 0.0f, 0.0f};
  f32x4 pv[4] = {};

#pragma unroll
  for (int c = 0; c < 2; c++) {
#pragma unroll
    for (int j = 0; j < 4; j++) {
      const int kk = k0w + c * 64 + j * 16 + lr;  // this lane's k-column
      f32x4 acc = {};
#pragma unroll
      for (int s = 0; s < 2; s++) {
        const size_t ko = (hbase + kk) * (size_t)DHh + s * 32 + lg * 8;
        const short8 bh8 = *(const short8*)&khh[ko];
        const short8 bl8 = *(const short8*)&khl[ko];
        acc = __builtin_amdgcn_mfma_f32_16x16x32_bf16(aqh[s], bh8, acc, 0, 0, 0);
        acc = __builtin_amdgcn_mfma_f32_16x16x32_bf16(aqh[s], bl8, acc, 0, 0, 0);
        acc = __builtin_amdgcn_mfma_f32_16x16x32_bf16(aql[s], bh8, acc, 0, 0, 0);
      }
      const float k2v = k2n[hbase + kk];
      const float l1v = lam1[hbase + kk];
#pragma unroll
      for (int r = 0; r < 4; r++) {
        const float e = score_e(acc[r], q2r[r], k2v, scale, sone);
        E[c * 16 + j * 4 + r] = e;
        rs[r] += e;
        __hip_bfloat16 ebh = __float2bfloat16(e);
        wlds[w][(lg * 4 + r) * 72 + j * 16 + lr] = *(unsigned short*)&ebh;
        dacc[r] += __bfloat162float(ebh) * l1v;  // den from SAME rounded w
      }
    }
    // PV for this 64-k chunk: A = w-hi from wlds, B = (lam v)^T direct global.
#pragma unroll
    for (int s = 0; s < 2; s++) {
      const short8 wa = *(const short8*)&wlds[w][lr * 72 + s * 32 + lg * 8];
#pragma unroll
      for (int n = 0; n < 4; n++) {
        const size_t vo = ((size_t)bh * DHh + n * 16 + lr) * (size_t)Ll + k0w +
                          c * 64 + s * 32 + lg * 8;
        const short8 vbh8 = *(const short8*)&vth[vo];
        const short8 vbl8 = *(const short8*)&vtl[vo];
        pv[n] = __builtin_amdgcn_mfma_f32_16x16x32_bf16(wa, vbh8, pv[n], 0, 0, 0);
        pv[n] = __builtin_amdgcn_mfma_f32_16x16x32_bf16(wa, vbl8, pv[n], 0, 0, 0);
      }
    }
  }

  // Intra-wave reduce over the 16 k-columns (lr) for rowsum and den.
#pragma unroll
  for (int r = 0; r < 4; r++) {
    float v = rs[r];
    v += __shfl_xor(v, 1, 64);
    v += __shfl_xor(v, 2, 64);
    v += __shfl_xor(v, 4, 64);
    v += __shfl_xor(v, 8, 64);
    rs[r] = v;
    float dv = dacc[r];
    dv += __shfl_xor(dv, 1, 64);
    dv += __shfl_xor(dv, 2, 64);
    dv += __shfl_xor(dv, 4, 64);
    dv += __shfl_xor(dv, 8, 64);
    dacc[r] = dv;
  }
  if (lr == 0) {
#pragma unroll
    for (int r = 0; r < 4; r++) rsred[w][lg * 4 + r] = rs[r];
  }
  if (w > 0) {
#pragma unroll
    for (int n = 0; n < 4; n++)
#pragma unroll
      for (int r = 0; r < 4; r++) pvred[w - 1][l][n * 4 + r] = pv[n][r];
#pragma unroll
    for (int r = 0; r < 4; r++) pvred[w - 1][l][16 + r] = dacc[r];
  }
  __syncthreads();

  // Normalized attention write (all waves, each its own k range).
  float rinv[4];
#pragma unroll
  for (int r = 0; r < 4; r++) {
    float tot = 0.0f;
#pragma unroll
    for (int ww = 0; ww < 8; ww++) tot += rsred[ww][lg * 4 + r];
    rinv[r] = 1.0f / tot;
  }
#pragma unroll
  for (int r = 0; r < 4; r++) {
    float* pr = attn + (hbase + q0 + lg * 4 + r) * (size_t)Ll + k0w + lr;
#pragma unroll
    for (int c = 0; c < 2; c++)
#pragma unroll
      for (int j = 0; j < 4; j++)
        pr[c * 64 + j * 16] = E[c * 16 + j * 4 + r] * rinv[r];
  }

  // Wave 0: total pv/den, midpoint epilogue, write yh.
  if (w == 0) {
#pragma unroll
    for (int ww = 0; ww < 7; ww++) {
#pragma unroll
      for (int n = 0; n < 4; n++)
#pragma unroll
        for (int r = 0; r < 4; r++) pv[n][r] += pvred[ww][l][n * 4 + r];
#pragma unroll
      for (int r = 0; r < 4; r++) dacc[r] += pvred[ww][l][16 + r];
    }
    const int b = bh / Hh, h = bh % Hh;
#pragma unroll
    for (int r = 0; r < 4; r++) {
      float den = dacc[r];
      if (fabsf(den) < 1e-10f) den = 1e-10f;
      const float dinv = 1.0f / den;
      float tm[4];
      float n2 = 0.0f;
#pragma unroll
      for (int n = 0; n < 4; n++) {
        tm[n] = pv[n][r] * dinv;
        n2 += tm[n] * tm[n];
      }
      n2 += __shfl_xor(n2, 1, 64);
      n2 += __shfl_xor(n2, 2, 64);
      n2 += __shfl_xor(n2, 4, 64);
      n2 += __shfl_xor(n2, 8, 64);
      const float nn = sqrtf(fmaxf(n2, EPSf * EPSf));
      const float nc = fminf(nn, MAXN);
      // tanh(artanh(nc)/2) = nc / (1 + sqrt(1 - nc^2))
      const float pn = nc / (1.0f + sqrtf(fmaxf(1.0f - nc * nc, 0.0f)));
      const float f = pn / nn * fminf(1.0f, MAXN / fmaxf(pn, EPSf));
      const int ql = q0 + lg * 4 + r;
#pragma unroll
      for (int n = 0; n < 4; n++)
        yh[(((size_t)(b * Ll + ql)) * Hh + h) * DHh + n * 16 + lr] = f * tm[n];
    }
  }
}

// ---------------------------------------------------------------------------
// beta_concat: per-head logmap0 / BETA_RATIO, then expmap0 over full D.
// ---------------------------------------------------------------------------
__global__ __launch_bounds__(768) void k_concat(
    const float* __restrict__ yh, float* __restrict__ yc, float beta_ratio) {
  const int t = threadIdx.x;
  const int row = blockIdx.x;
  const int w = t >> 6, lane = t & 63;
  __shared__ float red[12];
  const float ye = yh[(size_t)row * Dd + t];
  const float hs = wred64(ye * ye);
  const float hn = sqrtf(fmaxf(hs, EPSf * EPSf));
  const float cc = artanh_(fminf(hn, MAXN)) / hn / beta_ratio;
  const float ve = cc * ye;
  const float s = wred64(ve * ve);
  if (lane == 0) red[w] = s;
  __syncthreads();
  float n2 = 0.0f;
#pragma unroll
  for (int i = 0; i < 12; i++) n2 += red[i];
  const float n = sqrtf(fmaxf(n2, EPSf * EPSf));
  const float f = tanhf(n) / n;
  yc[(size_t)row * Dd + t] = f * ve;
}

// ---------------------------------------------------------------------------
// Final: mobius_matvec scaling (project), mobius_add with bias, project.
// ---------------------------------------------------------------------------
__global__ __launch_bounds__(768) void k_final(
    const float* __restrict__ yc, const float* __restrict__ mp,
    const float* __restrict__ bp, float* __restrict__ out) {
  const int t = threadIdx.x;
  const int row = blockIdx.x;
  const int w = t >> 6, lane = t & 63;
  __shared__ float red[12];
  auto blockSum = [&](float v) -> float {
    __syncthreads();
    const float s = wred64(v);
    if (lane == 0) red[w] = s;
    __syncthreads();
    float tot = 0.0f;
#pragma unroll
    for (int i = 0; i < 12; i++) tot += red[i];
    return tot;
  };
  const float xe = yc[(size_t)row * Dd + t];
  const float me = mp[(size_t)row * Dd + t];
  const float be = bp[t];
  const float xn2 = blockSum(xe * xe);
  const float xn = sqrtf(fmaxf(xn2, EPSf * EPSf));
  const float arx = artanh_(fminf(xn, MAXN));
  const float mn2 = blockSum(me * me);
  const float mxn = sqrtf(fmaxf(mn2, EPSf * EPSf));
  const float pn = tanhf(mxn / xn * arx);
  const float c1 = pn / mxn * fminf(1.0f, MAXN / fmaxf(pn, EPSf));
  const float mme = c1 * me;
  const float x2 = blockSum(mme * mme);
  const float y2 = blockSum(be * be);
  const float xy = blockSum(mme * be);
  const float nume = (1.0f + 2.0f * xy + y2) * mme + (1.0f - x2) * be;
  const float den = fmaxf(1.0f + 2.0f * xy + x2 * y2, EPSf);
  const float re = nume / den;
  const float rn2 = blockSum(re * re);
  const float rn = sqrtf(fmaxf(rn2, EPSf * EPSf));
  const float f = fminf(1.0f, MAXN / rn);
  out[(size_t)row * Dd + t] = f * re;
}

}  // namespace

extern "C" void kernel_launch(void* const* d_in, const int* in_sizes, int n_in,
                              void* d_out, int out_size, void* d_ws,
                              size_t ws_size, hipStream_t stream) {
  const float* x = (const float*)d_in[0];
  const float* Wq = (const float*)d_in[1];
  const float* Wk = (const float*)d_in[2];
  const float* Wv = (const float*)d_in[3];
  const float* Wp = (const float*)d_in[4];
  const float* bp = (const float*)d_in[5];
  const float* scale = (const float*)d_in[6];

  float* out = (float*)d_out;
  float* y_out = out;                        // (B,L,D)
  float* attn = out + (size_t)Bb * Ll * Dd;  // (B,H,L,L)

  const size_t NH = (size_t)Bb * Hh * Ll;  // 98304
  const size_t RD = (size_t)Bb * Ll * Dd;  // 6291456

  unsigned short* u = (unsigned short*)d_ws;
  unsigned short* qhh = u;
  unsigned short* qhl = u + RD;
  unsigned short* khh = u + 2 * RD;
  unsigned short* khl = u + 3 * RD;
  unsigned short* vth = u + 4 * RD;
  unsigned short* vtl = u + 5 * RD;
  unsigned short* vhh = u + 6 * RD;  // dead after k_vt
  unsigned short* vhl_ = u + 7 * RD;
  unsigned short* whi = u + 8 * RD;  // 4*DD ushorts
  unsigned short* wlo = whi + 4 * (size_t)DDm;
  float* fb = (float*)(wlo + 4 * (size_t)DDm);
  float* q2n = fb;
  float* k2n = fb + NH;
  float* lam1 = fb + 2 * NH;
  // overlays (dead-region reuse after k_attn_fused):
  float* yh = (float*)(u + 6 * RD);   // RD floats over vhh/vhl_
  float* yc = (float*)u;              // RD floats over qhh/qhl
  unsigned short* ychi = u + 2 * RD;  // over khh
  unsigned short* yclo = u + 3 * RD;  // over khl
  float* mp = (float*)(u + 4 * RD);   // RD floats over vth/vtl

  // GEMM outputs + bf16 x staged in the not-yet-written attn region.
  float* mq = attn;
  float* mk = attn + RD;
  float* mv = attn + 2 * RD;
  unsigned short* xhi = (unsigned short*)(attn + 3 * RD);
  unsigned short* xlo = xhi + RD;

  const double br =
      exp(lgamma(DHh / 2.0) + lgamma(0.5) - lgamma(DHh / 2.0 + 0.5) -
          (lgamma(Dd / 2.0) + lgamma(0.5) - lgamma(Dd / 2.0 + 0.5)));
  const float beta_ratio = (float)br;

  (void)in_sizes; (void)n_in; (void)out_size; (void)ws_size;

  k_cvt<<<dim3((int)(RD / 4 / 256)), dim3(256), 0, stream>>>(x, xhi, xlo,
                                                             (int)(RD / 4));
  k_cvt<<<dim3(DDm / 4 / 256), dim3(256), 0, stream>>>(Wq, whi, wlo, DDm / 4);
  k_cvt<<<dim3(DDm / 4 / 256), dim3(256), 0, stream>>>(
      Wk, whi + (size_t)DDm, wlo + (size_t)DDm, DDm / 4);
  k_cvt<<<dim3(DDm / 4 / 256), dim3(256), 0, stream>>>(
      Wv, whi + 2 * (size_t)DDm, wlo + 2 * (size_t)DDm, DDm / 4);
  k_cvt<<<dim3(DDm / 4 / 256), dim3(256), 0, stream>>>(
      Wp, whi + 3 * (size_t)DDm, wlo + 3 * (size_t)DDm, DDm / 4);

  k_gemm_bf16s<<<dim3(Dd / 128, (Bb * Ll) / 128, 3), dim3(256), 0, stream>>>(
      xhi, xlo, whi, wlo, mq);

  k_qkv_transform<<<dim3(Bb * Ll), dim3(768), 0, stream>>>(
      x, mq, mk, mv, qhh, qhl, khh, khl, vhh, vhl_, q2n, k2n, lam1,
      beta_ratio);

  k_vt<<<dim3(16, Bb * Hh), dim3(256), 0, stream>>>(vhh, vhl_, vth, vtl);

  k_attn_fused<<<dim3(Ll / 16, Bb * Hh), dim3(512), 0, stream>>>(
      qhh, qhl, khh, khl, vth, vtl, q2n, k2n, lam1, scale, attn, yh);

  k_concat<<<dim3(Bb * Ll), dim3(768), 0, stream>>>(yh, yc, beta_ratio);

  k_cvt<<<dim3((int)(RD / 4 / 256)), dim3(256), 0, stream>>>(yc, ychi, yclo,
                                                             (int)(RD / 4));
  k_gemm_bf16s<<<dim3(Dd / 128, (Bb * Ll) / 128, 1), dim3(256), 0, stream>>>(
      ychi, yclo, whi + 3 * (size_t)DDm, wlo + 3 * (size_t)DDm, mp);

  k_final<<<dim3(Bb * Ll), dim3(768), 0, stream>>>(yc, mp, bp, y_out);
}

// Round 5
// 809.313 us; speedup vs baseline: 1.1241x; 1.1241x over previous
//
#include <hip/hip_runtime.h>
#include <hip/hip_bf16.h>
#include <math.h>

namespace {

constexpr int Bb = 8, Ll = 1024, Dd = 768, Hh = 12, DHh = 64;
constexpr int DDm = Dd * Dd;
constexpr float MAXN = 1.0f - 1e-5f;
constexpr float EPSf = 1e-15f;

typedef __attribute__((ext_vector_type(8))) short short8;
typedef __attribute__((ext_vector_type(4))) short short4v;
typedef __attribute__((ext_vector_type(4))) float f32x4;

__device__ __forceinline__ float wred64(float v) {
#pragma unroll
  for (int m = 32; m >= 1; m >>= 1) v += __shfl_xor(v, m, 64);
  return v;
}

__device__ __forceinline__ float artanh_(float x) {
  return 0.5f * logf((1.0f + x) / (1.0f - x));
}

__device__ __forceinline__ void bsplit(float x, unsigned short& h,
                                       unsigned short& l) {
  __hip_bfloat16 hb = __float2bfloat16(x);
  const float hf = __bfloat162float(hb);
  __hip_bfloat16 lb = __float2bfloat16(x - hf);
  h = *(unsigned short*)&hb;
  l = *(unsigned short*)&lb;
}

// e = exp(-scale * 2*artanh(t)) = ((1-t)/(1+t))^scale ; fast path scale==1
__device__ __forceinline__ float score_e(float qk, float q2v, float k2v,
                                         float scale, bool sone) {
  const float diff2 = fmaxf(q2v + k2v - 2.0f * qk, 0.0f);
  const float den = fmaxf(1.0f - 2.0f * qk + q2v * k2v, EPSf);
  const float r = diff2 * __builtin_amdgcn_rcpf(den);
  const float t = fminf(sqrtf(fmaxf(r, 0.0f)), MAXN);
  const float p = (1.0f - t) * __builtin_amdgcn_rcpf(1.0f + t);
  return sone ? p : expf(scale * logf(p));
}

// ---------------------------------------------------------------------------
// Split fp32 -> bf16 hi + bf16 lo.
// ---------------------------------------------------------------------------
__global__ __launch_bounds__(256) void k_cvt(const float* __restrict__ in,
                                             unsigned short* __restrict__ hi,
                                             unsigned short* __restrict__ lo,
                                             int n4) {
  const int i = blockIdx.x * 256 + threadIdx.x;
  if (i >= n4) return;
  float4 v = ((const float4*)in)[i];
  float xs[4] = {v.x, v.y, v.z, v.w};
  unsigned short hs[4], ls[4];
#pragma unroll
  for (int j = 0; j < 4; j++) bsplit(xs[j], hs[j], ls[j]);
  ((ushort4*)hi)[i] = make_ushort4(hs[0], hs[1], hs[2], hs[3]);
  ((ushort4*)lo)[i] = make_ushort4(ls[0], ls[1], ls[2], ls[3]);
}

// ---------------------------------------------------------------------------
// bf16-split MFMA GEMM: C = A @ W^T (~fp32 precision).
// ---------------------------------------------------------------------------
__global__ __launch_bounds__(256) void k_gemm_bf16s(
    const unsigned short* __restrict__ Ahi, const unsigned short* __restrict__ Alo,
    const unsigned short* __restrict__ Whi, const unsigned short* __restrict__ Wlo,
    float* __restrict__ C) {
  constexpr int K = Dd, N = Dd;
  const int z = blockIdx.z;
  const unsigned short* Bh = Whi + (size_t)z * DDm;
  const unsigned short* Bl = Wlo + (size_t)z * DDm;
  float* Cz = C + (size_t)z * 8192 * N;
  __shared__ __align__(16) unsigned short sAh[128 * 32];
  __shared__ __align__(16) unsigned short sAl[128 * 32];
  __shared__ __align__(16) unsigned short sBh[128 * 32];
  __shared__ __align__(16) unsigned short sBl[128 * 32];
  const int t = threadIdx.x;
  const int l = t & 63, wid = t >> 6;
  const int wr = wid >> 1, wc = wid & 1;
  const int m0 = blockIdx.y * 128, n0 = blockIdx.x * 128;

  const int r0 = t >> 2, kf0 = t & 3;
  const int r1 = (t + 256) >> 2, kf1 = (t + 256) & 3;
  const int sw0 = r0 * 32 + ((kf0 ^ ((r0 >> 1) & 3)) << 3);
  const int sw1 = r1 * 32 + ((kf1 ^ ((r1 >> 1) & 3)) << 3);
  const size_t ga0 = (size_t)(m0 + r0) * K + kf0 * 8;
  const size_t ga1 = (size_t)(m0 + r1) * K + kf1 * 8;
  const size_t gb0 = (size_t)(n0 + r0) * K + kf0 * 8;
  const size_t gb1 = (size_t)(n0 + r1) * K + kf1 * 8;

  const int lar = l & 15, lkf = l >> 4;

  f32x4 acc[4][4] = {};

  for (int k0 = 0; k0 < K; k0 += 32) {
    const short8 vah0 = *(const short8*)&Ahi[ga0 + k0];
    const short8 vah1 = *(const short8*)&Ahi[ga1 + k0];
    const short8 val0 = *(const short8*)&Alo[ga0 + k0];
    const short8 val1 = *(const short8*)&Alo[ga1 + k0];
    const short8 vbh0 = *(const short8*)&Bh[gb0 + k0];
    const short8 vbh1 = *(const short8*)&Bh[gb1 + k0];
    const short8 vbl0 = *(const short8*)&Bl[gb0 + k0];
    const short8 vbl1 = *(const short8*)&Bl[gb1 + k0];
    __syncthreads();
    *(short8*)&sAh[sw0] = vah0;
    *(short8*)&sAh[sw1] = vah1;
    *(short8*)&sAl[sw0] = val0;
    *(short8*)&sAl[sw1] = val1;
    *(short8*)&sBh[sw0] = vbh0;
    *(short8*)&sBh[sw1] = vbh1;
    *(short8*)&sBl[sw0] = vbl0;
    *(short8*)&sBl[sw1] = vbl1;
    __syncthreads();

    short8 ah[4], al[4], bh[4], bl[4];
#pragma unroll
    for (int f = 0; f < 4; f++) {
      const int ra = wr * 64 + f * 16 + lar;
      const int ia = ra * 32 + ((lkf ^ ((ra >> 1) & 3)) << 3);
      ah[f] = *(const short8*)&sAh[ia];
      al[f] = *(const short8*)&sAl[ia];
      const int rb = wc * 64 + f * 16 + lar;
      const int ib = rb * 32 + ((lkf ^ ((rb >> 1) & 3)) << 3);
      bh[f] = *(const short8*)&sBh[ib];
      bl[f] = *(const short8*)&sBl[ib];
    }
#pragma unroll
    for (int i = 0; i < 4; i++)
#pragma unroll
      for (int j = 0; j < 4; j++) {
        acc[i][j] = __builtin_amdgcn_mfma_f32_16x16x32_bf16(ah[i], bh[j],
                                                            acc[i][j], 0, 0, 0);
        acc[i][j] = __builtin_amdgcn_mfma_f32_16x16x32_bf16(ah[i], bl[j],
                                                            acc[i][j], 0, 0, 0);
        acc[i][j] = __builtin_amdgcn_mfma_f32_16x16x32_bf16(al[i], bh[j],
                                                            acc[i][j], 0, 0, 0);
      }
  }

#pragma unroll
  for (int i = 0; i < 4; i++)
#pragma unroll
    for (int j = 0; j < 4; j++) {
      const int row = m0 + wr * 64 + i * 16 + (l >> 4) * 4;
      const int col = n0 + wc * 64 + j * 16 + (l & 15);
      const f32x4 v = acc[i][j];
#pragma unroll
      for (int q = 0; q < 4; q++) Cz[(size_t)(row + q) * N + col] = v[q];
    }
}

// ---------------------------------------------------------------------------
// Per-row transform; emits q/k/(lam*v) as bf16 hi/lo + per-head stats.
// ---------------------------------------------------------------------------
__global__ __launch_bounds__(768) void k_qkv_transform(
    const float* __restrict__ x,
    const float* __restrict__ mq, const float* __restrict__ mk,
    const float* __restrict__ mv,
    unsigned short* __restrict__ qhh, unsigned short* __restrict__ qhl,
    unsigned short* __restrict__ khh, unsigned short* __restrict__ khl,
    unsigned short* __restrict__ vhh, unsigned short* __restrict__ vhl_,
    float* __restrict__ q2n, float* __restrict__ k2n,
    float* __restrict__ lam1, float beta_ratio) {
  const int t = threadIdx.x;
  const int row = blockIdx.x;  // b*L + l
  const int b = row >> 10, l = row & 1023;
  const int w = t >> 6, lane = t & 63;
  __shared__ float red[12];

  const float xe = x[(size_t)row * Dd + t];
  float s = wred64(xe * xe);
  if (lane == 0) red[w] = s;
  __syncthreads();
  float xn2 = 0.0f;
#pragma unroll
  for (int i = 0; i < 12; i++) xn2 += red[i];
  const float xn = sqrtf(fmaxf(xn2, EPSf * EPSf));
  const float arx = artanh_(fminf(xn, MAXN));

  const float* mptr[3] = {mq, mk, mv};
#pragma unroll
  for (int mi = 0; mi < 3; mi++) {
    const float me = mptr[mi][(size_t)row * Dd + t];
    __syncthreads();
    float s2 = wred64(me * me);
    if (lane == 0) red[w] = s2;
    __syncthreads();
    float mn2 = 0.0f;
#pragma unroll
    for (int i = 0; i < 12; i++) mn2 += red[i];
    const float mxn = sqrtf(fmaxf(mn2, EPSf * EPSf));
    const float pn = tanhf(mxn / xn * arx);
    const float c1 = pn / mxn * fminf(1.0f, MAXN / fmaxf(pn, EPSf));
    const float nn = fmaxf(fminf(pn, MAXN), EPSf);
    const float c2 = artanh_(nn) / nn;
    const float ve = c2 * c1 * me * beta_ratio;
    const float hs = wred64(ve * ve);
    const float hn = sqrtf(fmaxf(hs, EPSf * EPSf));
    const float th = tanhf(hn);
    const float oe = th / hn * ve;
    const size_t hidx = (size_t)(b * Hh + w) * Ll + l;
    const size_t oidx = hidx * DHh + lane;
    unsigned short hu, lu;
    if (mi == 0) {
      bsplit(oe, hu, lu);
      qhh[oidx] = hu; qhl[oidx] = lu;
      if (lane == 0) q2n[hidx] = th * th;
    } else if (mi == 1) {
      bsplit(oe, hu, lu);
      khh[oidx] = hu; khl[oidx] = lu;
      if (lane == 0) k2n[hidx] = th * th;
    } else {
      const float lam = 2.0f / fmaxf(1.0f - th * th, EPSf);
      bsplit(lam * oe, hu, lu);
      vhh[oidx] = hu; vhl_[oidx] = lu;
      if (lane == 0) lam1[hidx] = lam - 1.0f;
    }
  }
}

// ---------------------------------------------------------------------------
// Transpose lam*v per head: [k][d] -> [d][k] (bf16 hi/lo).
// ---------------------------------------------------------------------------
__global__ __launch_bounds__(256) void k_vt(const unsigned short* __restrict__ vh,
                                            const unsigned short* __restrict__ vl,
                                            unsigned short* __restrict__ th,
                                            unsigned short* __restrict__ tl) {
  __shared__ __align__(16) unsigned short sh[64 * 72];
  __shared__ __align__(16) unsigned short sl[64 * 72];
  const int t = threadIdx.x;
  const int bh = blockIdx.y, c = blockIdx.x;
  const size_t ibase = ((size_t)bh * Ll + c * 64) * DHh;
#pragma unroll
  for (int u = 0; u < 2; u++) {
    const int ch = t + u * 256, r = ch >> 3, f = ch & 7;
    *(short8*)&sh[r * 72 + f * 8] = *(const short8*)&vh[ibase + r * DHh + f * 8];
    *(short8*)&sl[r * 72 + f * 8] = *(const short8*)&vl[ibase + r * DHh + f * 8];
  }
  __syncthreads();
#pragma unroll
  for (int u = 0; u < 2; u++) {
    const int ch = t + u * 256, d = ch >> 3, kb = ch & 7;
    short8 oh, ol;
#pragma unroll
    for (int i = 0; i < 8; i++) {
      oh[i] = (short)sh[(kb * 8 + i) * 72 + d];
      ol[i] = (short)sl[(kb * 8 + i) * 72 + d];
    }
    const size_t ob = ((size_t)bh * DHh + d) * Ll + c * 64 + kb * 8;
    *(short8*)&th[ob] = oh;
    *(short8*)&tl[ob] = ol;
  }
}

// ---------------------------------------------------------------------------
// Fused attention (staged): grid (16, B*H), 256 threads (4 waves).
// Block = 64 q-rows; wave w owns q-rows [w*16, w*16+16), all 1024 k.
// Swapped-operand QK^T: acc = mfma(Kfrag, Qfrag) => lane holds 4 consecutive
// k (regs) for ONE q (lane&15) -> float4 attn stores, cheap reductions.
// Loop 1: rowsum only. Loop 2: recompute e (K restage is L2-hot), write
// normalized attn, PV (w-hi only) + Mobius midpoint epilogue.
// ---------------------------------------------------------------------------
__global__ __launch_bounds__(256) void k_attn2(
    const unsigned short* __restrict__ qhh, const unsigned short* __restrict__ qhl,
    const unsigned short* __restrict__ khh, const unsigned short* __restrict__ khl,
    const unsigned short* __restrict__ vth, const unsigned short* __restrict__ vtl,
    const float* __restrict__ q2n, const float* __restrict__ k2n,
    const float* __restrict__ lam1, const float* __restrict__ scale_p,
    float* __restrict__ attn, float* __restrict__ yh) {
  __shared__ __align__(16) unsigned short kldsh[64 * 72];
  __shared__ __align__(16) unsigned short kldsl[64 * 72];
  __shared__ __align__(16) unsigned short vldsh[64 * 72];
  __shared__ __align__(16) unsigned short vldsl[64 * 72];
  __shared__ __align__(16) unsigned short wlds[4][16 * 72];
  __shared__ __align__(16) float k2s[64];
  __shared__ __align__(16) float l1s[64];
  __shared__ float dred[4][16];
  const int t = threadIdx.x, l = t & 63, w = t >> 6;
  const int lr = l & 15, lg = l >> 4;
  const int bh = blockIdx.y, q0 = blockIdx.x * 64;
  const size_t hbase = (size_t)bh * Ll;
  const float scale = scale_p[0];
  const bool sone = (scale == 1.0f);

  // Q fragments (B operand): col = q = q0 + w*16 + lr, slice s*32 + lg*8.
  short8 aqh[2], aql[2];
#pragma unroll
  for (int s = 0; s < 2; s++) {
    const size_t off = (hbase + q0 + w * 16 + lr) * (size_t)DHh + s * 32 + lg * 8;
    aqh[s] = *(const short8*)&qhh[off];
    aql[s] = *(const short8*)&qhl[off];
  }
  const float q2v = q2n[hbase + q0 + w * 16 + lr];

  const int sr0 = t >> 3, sf0 = t & 7;
  const int sr1 = (t + 256) >> 3, sf1 = (t + 256) & 7;

  // ---- Loop 1: rowsums ----
  float rs = 0.0f;
  for (int c = 0; c < 16; c++) {
    const size_t kg0 = (hbase + c * 64 + sr0) * (size_t)DHh + sf0 * 8;
    const size_t kg1 = (hbase + c * 64 + sr1) * (size_t)DHh + sf1 * 8;
    const short8 pkh0 = *(const short8*)&khh[kg0];
    const short8 pkh1 = *(const short8*)&khh[kg1];
    const short8 pkl0 = *(const short8*)&khl[kg0];
    const short8 pkl1 = *(const short8*)&khl[kg1];
    float k2r = 0.0f;
    if (t < 64) k2r = k2n[hbase + c * 64 + t];
    __syncthreads();
    *(short8*)&kldsh[sr0 * 72 + sf0 * 8] = pkh0;
    *(short8*)&kldsh[sr1 * 72 + sf1 * 8] = pkh1;
    *(short8*)&kldsl[sr0 * 72 + sf0 * 8] = pkl0;
    *(short8*)&kldsl[sr1 * 72 + sf1 * 8] = pkl1;
    if (t < 64) k2s[t] = k2r;
    __syncthreads();
#pragma unroll
    for (int j = 0; j < 4; j++) {
      f32x4 acc = {};
#pragma unroll
      for (int s = 0; s < 2; s++) {
        const int ko = (j * 16 + lr) * 72 + s * 32 + lg * 8;
        const short8 kfh = *(const short8*)&kldsh[ko];
        const short8 kfl = *(const short8*)&kldsl[ko];
        acc = __builtin_amdgcn_mfma_f32_16x16x32_bf16(kfh, aqh[s], acc, 0, 0, 0);
        acc = __builtin_amdgcn_mfma_f32_16x16x32_bf16(kfh, aql[s], acc, 0, 0, 0);
        acc = __builtin_amdgcn_mfma_f32_16x16x32_bf16(kfl, aqh[s], acc, 0, 0, 0);
      }
      const float4 k2q = *(const float4*)&k2s[j * 16 + lg * 4];
      const float kq[4] = {k2q.x, k2q.y, k2q.z, k2q.w};
#pragma unroll
      for (int r = 0; r < 4; r++)
        rs += score_e(acc[r], q2v, kq[r], scale, sone);
    }
  }
  rs += __shfl_xor(rs, 16, 64);
  rs += __shfl_xor(rs, 32, 64);
  const float rinv = 1.0f / rs;

  // ---- Loop 2: write normalized attn + PV + midpoint ----
  f32x4 pv[4] = {};
  float dacc = 0.0f;
  for (int c = 0; c < 16; c++) {
    const size_t kg0 = (hbase + c * 64 + sr0) * (size_t)DHh + sf0 * 8;
    const size_t kg1 = (hbase + c * 64 + sr1) * (size_t)DHh + sf1 * 8;
    const short8 pkh0 = *(const short8*)&khh[kg0];
    const short8 pkh1 = *(const short8*)&khh[kg1];
    const short8 pkl0 = *(const short8*)&khl[kg0];
    const short8 pkl1 = *(const short8*)&khl[kg1];
    const size_t vg0 = ((size_t)bh * DHh + sr0) * (size_t)Ll + c * 64 + sf0 * 8;
    const size_t vg1 = ((size_t)bh * DHh + sr1) * (size_t)Ll + c * 64 + sf1 * 8;
    const short8 pvh0 = *(const short8*)&vth[vg0];
    const short8 pvh1 = *(const short8*)&vth[vg1];
    const short8 pvl0 = *(const short8*)&vtl[vg0];
    const short8 pvl1 = *(const short8*)&vtl[vg1];
    float k2r = 0.0f, l1r = 0.0f;
    if (t < 64) {
      k2r = k2n[hbase + c * 64 + t];
      l1r = lam1[hbase + c * 64 + t];
    }
    __syncthreads();
    *(short8*)&kldsh[sr0 * 72 + sf0 * 8] = pkh0;
    *(short8*)&kldsh[sr1 * 72 + sf1 * 8] = pkh1;
    *(short8*)&kldsl[sr0 * 72 + sf0 * 8] = pkl0;
    *(short8*)&kldsl[sr1 * 72 + sf1 * 8] = pkl1;
    *(short8*)&vldsh[sr0 * 72 + sf0 * 8] = pvh0;
    *(short8*)&vldsh[sr1 * 72 + sf1 * 8] = pvh1;
    *(short8*)&vldsl[sr0 * 72 + sf0 * 8] = pvl0;
    *(short8*)&vldsl[sr1 * 72 + sf1 * 8] = pvl1;
    if (t < 64) {
      k2s[t] = k2r;
      l1s[t] = l1r;
    }
    __syncthreads();
#pragma unroll
    for (int j = 0; j < 4; j++) {
      f32x4 acc = {};
#pragma unroll
      for (int s = 0; s < 2; s++) {
        const int ko = (j * 16 + lr) * 72 + s * 32 + lg * 8;
        const short8 kfh = *(const short8*)&kldsh[ko];
        const short8 kfl = *(const short8*)&kldsl[ko];
        acc = __builtin_amdgcn_mfma_f32_16x16x32_bf16(kfh, aqh[s], acc, 0, 0, 0);
        acc = __builtin_amdgcn_mfma_f32_16x16x32_bf16(kfh, aql[s], acc, 0, 0, 0);
        acc = __builtin_amdgcn_mfma_f32_16x16x32_bf16(kfl, aqh[s], acc, 0, 0, 0);
      }
      const float4 k2q = *(const float4*)&k2s[j * 16 + lg * 4];
      const float4 l1q = *(const float4*)&l1s[j * 16 + lg * 4];
      const float kq[4] = {k2q.x, k2q.y, k2q.z, k2q.w};
      const float lq[4] = {l1q.x, l1q.y, l1q.z, l1q.w};
      float en[4];
      short4v wv;
#pragma unroll
      for (int r = 0; r < 4; r++) {
        const float e = score_e(acc[r], q2v, kq[r], scale, sone) * rinv;
        en[r] = e;
        __hip_bfloat16 eb = __float2bfloat16(e);
        wv[r] = *(short*)&eb;
        dacc += __bfloat162float(eb) * lq[r];  // den from SAME rounded w
      }
      float4 ef4 = make_float4(en[0], en[1], en[2], en[3]);
      *(float4*)&attn[(hbase + q0 + w * 16 + lr) * (size_t)Ll + c * 64 +
                      j * 16 + lg * 4] = ef4;
      *(short4v*)&wlds[w][lr * 72 + j * 16 + lg * 4] = wv;
    }
    // PV: A = w (16q x 64k, hi only), B = (lam v)^T staged [d][k].
#pragma unroll
    for (int s = 0; s < 2; s++) {
      const short8 wa = *(const short8*)&wlds[w][lr * 72 + s * 32 + lg * 8];
#pragma unroll
      for (int n = 0; n < 4; n++) {
        const int bo = (n * 16 + lr) * 72 + s * 32 + lg * 8;
        const short8 vbh8 = *(const short8*)&vldsh[bo];
        const short8 vbl8 = *(const short8*)&vldsl[bo];
        pv[n] = __builtin_amdgcn_mfma_f32_16x16x32_bf16(wa, vbh8, pv[n], 0, 0, 0);
        pv[n] = __builtin_amdgcn_mfma_f32_16x16x32_bf16(wa, vbl8, pv[n], 0, 0, 0);
      }
    }
  }

  // dacc: full row value lives spread over lg; reduce and redistribute.
  dacc += __shfl_xor(dacc, 16, 64);
  dacc += __shfl_xor(dacc, 32, 64);
  __syncthreads();
  if (lg == 0) dred[w][lr] = dacc;
  __syncthreads();

  const int b = bh / Hh, h = bh % Hh;
#pragma unroll
  for (int r = 0; r < 4; r++) {
    float den = dred[w][lg * 4 + r];
    if (fabsf(den) < 1e-10f) den = 1e-10f;
    const float dinv = 1.0f / den;
    float tm[4];
    float n2 = 0.0f;
#pragma unroll
    for (int n = 0; n < 4; n++) {
      tm[n] = pv[n][r] * dinv;
      n2 += tm[n] * tm[n];
    }
    n2 += __shfl_xor(n2, 1, 64);
    n2 += __shfl_xor(n2, 2, 64);
    n2 += __shfl_xor(n2, 4, 64);
    n2 += __shfl_xor(n2, 8, 64);
    const float nn = sqrtf(fmaxf(n2, EPSf * EPSf));
    const float nc = fminf(nn, MAXN);
    // tanh(artanh(nc)/2) = nc / (1 + sqrt(1 - nc^2))
    const float pn = nc / (1.0f + sqrtf(fmaxf(1.0f - nc * nc, 0.0f)));
    const float f = pn / nn * fminf(1.0f, MAXN / fmaxf(pn, EPSf));
    const int ql = q0 + w * 16 + lg * 4 + r;
#pragma unroll
    for (int n = 0; n < 4; n++)
      yh[(((size_t)(b * Ll + ql)) * Hh + h) * DHh + n * 16 + lr] = f * tm[n];
  }
}

// ---------------------------------------------------------------------------
// beta_concat: per-head logmap0 / BETA_RATIO, then expmap0 over full D.
// ---------------------------------------------------------------------------
__global__ __launch_bounds__(768) void k_concat(
    const float* __restrict__ yh, float* __restrict__ yc, float beta_ratio) {
  const int t = threadIdx.x;
  const int row = blockIdx.x;
  const int w = t >> 6, lane = t & 63;
  __shared__ float red[12];
  const float ye = yh[(size_t)row * Dd + t];
  const float hs = wred64(ye * ye);
  const float hn = sqrtf(fmaxf(hs, EPSf * EPSf));
  const float cc = artanh_(fminf(hn, MAXN)) / hn / beta_ratio;
  const float ve = cc * ye;
  const float s = wred64(ve * ve);
  if (lane == 0) red[w] = s;
  __syncthreads();
  float n2 = 0.0f;
#pragma unroll
  for (int i = 0; i < 12; i++) n2 += red[i];
  const float n = sqrtf(fmaxf(n2, EPSf * EPSf));
  const float f = tanhf(n) / n;
  yc[(size_t)row * Dd + t] = f * ve;
}

// ---------------------------------------------------------------------------
// Final: mobius_matvec scaling (project), mobius_add with bias, project.
// ---------------------------------------------------------------------------
__global__ __launch_bounds__(768) void k_final(
    const float* __restrict__ yc, const float* __restrict__ mp,
    const float* __restrict__ bp, float* __restrict__ out) {
  const int t = threadIdx.x;
  const int row = blockIdx.x;
  const int w = t >> 6, lane = t & 63;
  __shared__ float red[12];
  auto blockSum = [&](float v) -> float {
    __syncthreads();
    const float s = wred64(v);
    if (lane == 0) red[w] = s;
    __syncthreads();
    float tot = 0.0f;
#pragma unroll
    for (int i = 0; i < 12; i++) tot += red[i];
    return tot;
  };
  const float xe = yc[(size_t)row * Dd + t];
  const float me = mp[(size_t)row * Dd + t];
  const float be = bp[t];
  const float xn2 = blockSum(xe * xe);
  const float xn = sqrtf(fmaxf(xn2, EPSf * EPSf));
  const float arx = artanh_(fminf(xn, MAXN));
  const float mn2 = blockSum(me * me);
  const float mxn = sqrtf(fmaxf(mn2, EPSf * EPSf));
  const float pn = tanhf(mxn / xn * arx);
  const float c1 = pn / mxn * fminf(1.0f, MAXN / fmaxf(pn, EPSf));
  const float mme = c1 * me;
  const float x2 = blockSum(mme * mme);
  const float y2 = blockSum(be * be);
  const float xy = blockSum(mme * be);
  const float nume = (1.0f + 2.0f * xy + y2) * mme + (1.0f - x2) * be;
  const float den = fmaxf(1.0f + 2.0f * xy + x2 * y2, EPSf);
  const float re = nume / den;
  const float rn2 = blockSum(re * re);
  const float rn = sqrtf(fmaxf(rn2, EPSf * EPSf));
  const float f = fminf(1.0f, MAXN / rn);
  out[(size_t)row * Dd + t] = f * re;
}

}  // namespace

extern "C" void kernel_launch(void* const* d_in, const int* in_sizes, int n_in,
                              void* d_out, int out_size, void* d_ws,
                              size_t ws_size, hipStream_t stream) {
  const float* x = (const float*)d_in[0];
  const float* Wq = (const float*)d_in[1];
  const float* Wk = (const float*)d_in[2];
  const float* Wv = (const float*)d_in[3];
  const float* Wp = (const float*)d_in[4];
  const float* bp = (const float*)d_in[5];
  const float* scale = (const float*)d_in[6];

  float* out = (float*)d_out;
  float* y_out = out;                        // (B,L,D)
  float* attn = out + (size_t)Bb * Ll * Dd;  // (B,H,L,L)

  const size_t NH = (size_t)Bb * Hh * Ll;  // 98304
  const size_t RD = (size_t)Bb * Ll * Dd;  // 6291456

  unsigned short* u = (unsigned short*)d_ws;
  unsigned short* qhh = u;
  unsigned short* qhl = u + RD;
  unsigned short* khh = u + 2 * RD;
  unsigned short* khl = u + 3 * RD;
  unsigned short* vth = u + 4 * RD;
  unsigned short* vtl = u + 5 * RD;
  unsigned short* vhh = u + 6 * RD;  // dead after k_vt
  unsigned short* vhl_ = u + 7 * RD;
  unsigned short* whi = u + 8 * RD;  // 4*DD ushorts
  unsigned short* wlo = whi + 4 * (size_t)DDm;
  float* fb = (float*)(wlo + 4 * (size_t)DDm);
  float* q2n = fb;
  float* k2n = fb + NH;
  float* lam1 = fb + 2 * NH;
  // overlays (dead-region reuse after k_attn2):
  float* yh = (float*)(u + 6 * RD);   // RD floats over vhh/vhl_
  float* yc = (float*)u;              // RD floats over qhh/qhl
  unsigned short* ychi = u + 2 * RD;  // over khh
  unsigned short* yclo = u + 3 * RD;  // over khl
  float* mp = (float*)(u + 4 * RD);   // RD floats over vth/vtl

  // GEMM outputs + bf16 x staged in the not-yet-written attn region.
  float* mq = attn;
  float* mk = attn + RD;
  float* mv = attn + 2 * RD;
  unsigned short* xhi = (unsigned short*)(attn + 3 * RD);
  unsigned short* xlo = xhi + RD;

  const double br =
      exp(lgamma(DHh / 2.0) + lgamma(0.5) - lgamma(DHh / 2.0 + 0.5) -
          (lgamma(Dd / 2.0) + lgamma(0.5) - lgamma(Dd / 2.0 + 0.5)));
  const float beta_ratio = (float)br;

  (void)in_sizes; (void)n_in; (void)out_size; (void)ws_size;

  k_cvt<<<dim3((int)(RD / 4 / 256)), dim3(256), 0, stream>>>(x, xhi, xlo,
                                                             (int)(RD / 4));
  k_cvt<<<dim3(DDm / 4 / 256), dim3(256), 0, stream>>>(Wq, whi, wlo, DDm / 4);
  k_cvt<<<dim3(DDm / 4 / 256), dim3(256), 0, stream>>>(
      Wk, whi + (size_t)DDm, wlo + (size_t)DDm, DDm / 4);
  k_cvt<<<dim3(DDm / 4 / 256), dim3(256), 0, stream>>>(
      Wv, whi + 2 * (size_t)DDm, wlo + 2 * (size_t)DDm, DDm / 4);
  k_cvt<<<dim3(DDm / 4 / 256), dim3(256), 0, stream>>>(
      Wp, whi + 3 * (size_t)DDm, wlo + 3 * (size_t)DDm, DDm / 4);

  k_gemm_bf16s<<<dim3(Dd / 128, (Bb * Ll) / 128, 3), dim3(256), 0, stream>>>(
      xhi, xlo, whi, wlo, mq);

  k_qkv_transform<<<dim3(Bb * Ll), dim3(768), 0, stream>>>(
      x, mq, mk, mv, qhh, qhl, khh, khl, vhh, vhl_, q2n, k2n, lam1,
      beta_ratio);

  k_vt<<<dim3(16, Bb * Hh), dim3(256), 0, stream>>>(vhh, vhl_, vth, vtl);

  k_attn2<<<dim3(16, Bb * Hh), dim3(256), 0, stream>>>(
      qhh, qhl, khh, khl, vth, vtl, q2n, k2n, lam1, scale, attn, yh);

  k_concat<<<dim3(Bb * Ll), dim3(768), 0, stream>>>(yh, yc, beta_ratio);

  k_cvt<<<dim3((int)(RD / 4 / 256)), dim3(256), 0, stream>>>(yc, ychi, yclo,
                                                             (int)(RD / 4));
  k_gemm_bf16s<<<dim3(Dd / 128, (Bb * Ll) / 128, 1), dim3(256), 0, stream>>>(
      ychi, yclo, whi + 3 * (size_t)DDm, wlo + 3 * (size_t)DDm, mp);

  k_final<<<dim3(Bb * Ll), dim3(768), 0, stream>>>(yc, mp, bp, y_out);
}

// Round 6
// 799.764 us; speedup vs baseline: 1.1375x; 1.0119x over previous
//
#include <hip/hip_runtime.h>
#include <hip/hip_bf16.h>
#include <math.h>

namespace {

constexpr int Bb = 8, Ll = 1024, Dd = 768, Hh = 12, DHh = 64;
constexpr int DDm = Dd * Dd;
constexpr float MAXN = 1.0f - 1e-5f;
constexpr float EPSf = 1e-15f;

typedef __attribute__((ext_vector_type(8))) short short8;
typedef __attribute__((ext_vector_type(4))) short short4v;
typedef __attribute__((ext_vector_type(4))) float f32x4;

__device__ __forceinline__ float wred64(float v) {
#pragma unroll
  for (int m = 32; m >= 1; m >>= 1) v += __shfl_xor(v, m, 64);
  return v;
}

__device__ __forceinline__ float artanh_(float x) {
  return 0.5f * logf((1.0f + x) / (1.0f - x));
}

__device__ __forceinline__ void bsplit(float x, unsigned short& h,
                                       unsigned short& l) {
  __hip_bfloat16 hb = __float2bfloat16(x);
  const float hf = __bfloat162float(hb);
  __hip_bfloat16 lb = __float2bfloat16(x - hf);
  h = *(unsigned short*)&hb;
  l = *(unsigned short*)&lb;
}

// e = exp(-scale * 2*artanh(t)) = ((1-t)/(1+t))^scale ; fast path scale==1.
// t = sqrt(diff2/den) computed as diff2 * rsqrt(diff2*den)  (one trans less).
__device__ __forceinline__ float score_e(float qk, float q2v, float k2v,
                                         float scale, bool sone) {
  const float s2 = q2v + k2v;
  const float h1 = fmaf(q2v, k2v, 1.0f);
  const float qk2 = qk + qk;
  const float diff2 = fmaxf(s2 - qk2, 0.0f);
  const float den = h1 - qk2;  // > 0.5 for points with norm <= ~0.5
  const float t = fminf(
      diff2 * __builtin_amdgcn_rsqf(fmaxf(diff2 * den, 1e-30f)), MAXN);
  const float p = (1.0f - t) * __builtin_amdgcn_rcpf(1.0f + t);
  return sone ? p : expf(scale * logf(p));
}

// ---------------------------------------------------------------------------
// Split fp32 -> bf16 hi + bf16 lo.
// ---------------------------------------------------------------------------
__global__ __launch_bounds__(256) void k_cvt(const float* __restrict__ in,
                                             unsigned short* __restrict__ hi,
                                             unsigned short* __restrict__ lo,
                                             int n4) {
  const int i = blockIdx.x * 256 + threadIdx.x;
  if (i >= n4) return;
  float4 v = ((const float4*)in)[i];
  float xs[4] = {v.x, v.y, v.z, v.w};
  unsigned short hs[4], ls[4];
#pragma unroll
  for (int j = 0; j < 4; j++) bsplit(xs[j], hs[j], ls[j]);
  ((ushort4*)hi)[i] = make_ushort4(hs[0], hs[1], hs[2], hs[3]);
  ((ushort4*)lo)[i] = make_ushort4(ls[0], ls[1], ls[2], ls[3]);
}

// ---------------------------------------------------------------------------
// bf16-split MFMA GEMM: C = A @ W^T (~fp32 precision).
// ---------------------------------------------------------------------------
__global__ __launch_bounds__(256) void k_gemm_bf16s(
    const unsigned short* __restrict__ Ahi, const unsigned short* __restrict__ Alo,
    const unsigned short* __restrict__ Whi, const unsigned short* __restrict__ Wlo,
    float* __restrict__ C) {
  constexpr int K = Dd, N = Dd;
  const int z = blockIdx.z;
  const unsigned short* Bh = Whi + (size_t)z * DDm;
  const unsigned short* Bl = Wlo + (size_t)z * DDm;
  float* Cz = C + (size_t)z * 8192 * N;
  __shared__ __align__(16) unsigned short sAh[128 * 32];
  __shared__ __align__(16) unsigned short sAl[128 * 32];
  __shared__ __align__(16) unsigned short sBh[128 * 32];
  __shared__ __align__(16) unsigned short sBl[128 * 32];
  const int t = threadIdx.x;
  const int l = t & 63, wid = t >> 6;
  const int wr = wid >> 1, wc = wid & 1;
  const int m0 = blockIdx.y * 128, n0 = blockIdx.x * 128;

  const int r0 = t >> 2, kf0 = t & 3;
  const int r1 = (t + 256) >> 2, kf1 = (t + 256) & 3;
  const int sw0 = r0 * 32 + ((kf0 ^ ((r0 >> 1) & 3)) << 3);
  const int sw1 = r1 * 32 + ((kf1 ^ ((r1 >> 1) & 3)) << 3);
  const size_t ga0 = (size_t)(m0 + r0) * K + kf0 * 8;
  const size_t ga1 = (size_t)(m0 + r1) * K + kf1 * 8;
  const size_t gb0 = (size_t)(n0 + r0) * K + kf0 * 8;
  const size_t gb1 = (size_t)(n0 + r1) * K + kf1 * 8;

  const int lar = l & 15, lkf = l >> 4;

  f32x4 acc[4][4] = {};

  for (int k0 = 0; k0 < K; k0 += 32) {
    const short8 vah0 = *(const short8*)&Ahi[ga0 + k0];
    const short8 vah1 = *(const short8*)&Ahi[ga1 + k0];
    const short8 val0 = *(const short8*)&Alo[ga0 + k0];
    const short8 val1 = *(const short8*)&Alo[ga1 + k0];
    const short8 vbh0 = *(const short8*)&Bh[gb0 + k0];
    const short8 vbh1 = *(const short8*)&Bh[gb1 + k0];
    const short8 vbl0 = *(const short8*)&Bl[gb0 + k0];
    const short8 vbl1 = *(const short8*)&Bl[gb1 + k0];
    __syncthreads();
    *(short8*)&sAh[sw0] = vah0;
    *(short8*)&sAh[sw1] = vah1;
    *(short8*)&sAl[sw0] = val0;
    *(short8*)&sAl[sw1] = val1;
    *(short8*)&sBh[sw0] = vbh0;
    *(short8*)&sBh[sw1] = vbh1;
    *(short8*)&sBl[sw0] = vbl0;
    *(short8*)&sBl[sw1] = vbl1;
    __syncthreads();

    short8 ah[4], al[4], bh[4], bl[4];
#pragma unroll
    for (int f = 0; f < 4; f++) {
      const int ra = wr * 64 + f * 16 + lar;
      const int ia = ra * 32 + ((lkf ^ ((ra >> 1) & 3)) << 3);
      ah[f] = *(const short8*)&sAh[ia];
      al[f] = *(const short8*)&sAl[ia];
      const int rb = wc * 64 + f * 16 + lar;
      const int ib = rb * 32 + ((lkf ^ ((rb >> 1) & 3)) << 3);
      bh[f] = *(const short8*)&sBh[ib];
      bl[f] = *(const short8*)&sBl[ib];
    }
#pragma unroll
    for (int i = 0; i < 4; i++)
#pragma unroll
      for (int j = 0; j < 4; j++) {
        acc[i][j] = __builtin_amdgcn_mfma_f32_16x16x32_bf16(ah[i], bh[j],
                                                            acc[i][j], 0, 0, 0);
        acc[i][j] = __builtin_amdgcn_mfma_f32_16x16x32_bf16(ah[i], bl[j],
                                                            acc[i][j], 0, 0, 0);
        acc[i][j] = __builtin_amdgcn_mfma_f32_16x16x32_bf16(al[i], bh[j],
                                                            acc[i][j], 0, 0, 0);
      }
  }

#pragma unroll
  for (int i = 0; i < 4; i++)
#pragma unroll
    for (int j = 0; j < 4; j++) {
      const int row = m0 + wr * 64 + i * 16 + (l >> 4) * 4;
      const int col = n0 + wc * 64 + j * 16 + (l & 15);
      const f32x4 v = acc[i][j];
#pragma unroll
      for (int q = 0; q < 4; q++) Cz[(size_t)(row + q) * N + col] = v[q];
    }
}

// ---------------------------------------------------------------------------
// Per-row transform; emits q/k/(lam*v) as bf16 hi/lo + per-head stats.
// ---------------------------------------------------------------------------
__global__ __launch_bounds__(768) void k_qkv_transform(
    const float* __restrict__ x,
    const float* __restrict__ mq, const float* __restrict__ mk,
    const float* __restrict__ mv,
    unsigned short* __restrict__ qhh, unsigned short* __restrict__ qhl,
    unsigned short* __restrict__ khh, unsigned short* __restrict__ khl,
    unsigned short* __restrict__ vhh, unsigned short* __restrict__ vhl_,
    float* __restrict__ q2n, float* __restrict__ k2n,
    float* __restrict__ lam1, float beta_ratio) {
  const int t = threadIdx.x;
  const int row = blockIdx.x;  // b*L + l
  const int b = row >> 10, l = row & 1023;
  const int w = t >> 6, lane = t & 63;
  __shared__ float red[12];

  const float xe = x[(size_t)row * Dd + t];
  float s = wred64(xe * xe);
  if (lane == 0) red[w] = s;
  __syncthreads();
  float xn2 = 0.0f;
#pragma unroll
  for (int i = 0; i < 12; i++) xn2 += red[i];
  const float xn = sqrtf(fmaxf(xn2, EPSf * EPSf));
  const float arx = artanh_(fminf(xn, MAXN));

  const float* mptr[3] = {mq, mk, mv};
#pragma unroll
  for (int mi = 0; mi < 3; mi++) {
    const float me = mptr[mi][(size_t)row * Dd + t];
    __syncthreads();
    float s2 = wred64(me * me);
    if (lane == 0) red[w] = s2;
    __syncthreads();
    float mn2 = 0.0f;
#pragma unroll
    for (int i = 0; i < 12; i++) mn2 += red[i];
    const float mxn = sqrtf(fmaxf(mn2, EPSf * EPSf));
    const float pn = tanhf(mxn / xn * arx);
    const float c1 = pn / mxn * fminf(1.0f, MAXN / fmaxf(pn, EPSf));
    const float nn = fmaxf(fminf(pn, MAXN), EPSf);
    const float c2 = artanh_(nn) / nn;
    const float ve = c2 * c1 * me * beta_ratio;
    const float hs = wred64(ve * ve);
    const float hn = sqrtf(fmaxf(hs, EPSf * EPSf));
    const float th = tanhf(hn);
    const float oe = th / hn * ve;
    const size_t hidx = (size_t)(b * Hh + w) * Ll + l;
    const size_t oidx = hidx * DHh + lane;
    unsigned short hu, lu;
    if (mi == 0) {
      bsplit(oe, hu, lu);
      qhh[oidx] = hu; qhl[oidx] = lu;
      if (lane == 0) q2n[hidx] = th * th;
    } else if (mi == 1) {
      bsplit(oe, hu, lu);
      khh[oidx] = hu; khl[oidx] = lu;
      if (lane == 0) k2n[hidx] = th * th;
    } else {
      const float lam = 2.0f / fmaxf(1.0f - th * th, EPSf);
      bsplit(lam * oe, hu, lu);
      vhh[oidx] = hu; vhl_[oidx] = lu;
      if (lane == 0) lam1[hidx] = lam - 1.0f;
    }
  }
}

// ---------------------------------------------------------------------------
// Transpose lam*v per head: [k][d] -> [d][k] (bf16 hi/lo).
// ---------------------------------------------------------------------------
__global__ __launch_bounds__(256) void k_vt(const unsigned short* __restrict__ vh,
                                            const unsigned short* __restrict__ vl,
                                            unsigned short* __restrict__ th,
                                            unsigned short* __restrict__ tl) {
  __shared__ __align__(16) unsigned short sh[64 * 72];
  __shared__ __align__(16) unsigned short sl[64 * 72];
  const int t = threadIdx.x;
  const int bh = blockIdx.y, c = blockIdx.x;
  const size_t ibase = ((size_t)bh * Ll + c * 64) * DHh;
#pragma unroll
  for (int u = 0; u < 2; u++) {
    const int ch = t + u * 256, r = ch >> 3, f = ch & 7;
    *(short8*)&sh[r * 72 + f * 8] = *(const short8*)&vh[ibase + r * DHh + f * 8];
    *(short8*)&sl[r * 72 + f * 8] = *(const short8*)&vl[ibase + r * DHh + f * 8];
  }
  __syncthreads();
#pragma unroll
  for (int u = 0; u < 2; u++) {
    const int ch = t + u * 256, d = ch >> 3, kb = ch & 7;
    short8 oh, ol;
#pragma unroll
    for (int i = 0; i < 8; i++) {
      oh[i] = (short)sh[(kb * 8 + i) * 72 + d];
      ol[i] = (short)sl[(kb * 8 + i) * 72 + d];
    }
    const size_t ob = ((size_t)bh * DHh + d) * Ll + c * 64 + kb * 8;
    *(short8*)&th[ob] = oh;
    *(short8*)&tl[ob] = ol;
  }
}

// ---------------------------------------------------------------------------
// Fused attention, SINGLE pass. Grid (16, B*H), 256 threads (4 waves).
// Block = 64 q rows; wave w = q[w*16..w*16+16), all 1024 k in chunks of 32.
// Swapped QK^T (mfma(K,Q)): lane holds 4 consecutive k for one q.
// Writes UNNORMALIZED e (fp32) to attn + rowsums to scratch (k_norm
// normalizes in place afterwards). PV/den use unnormalized bf16 weights
// (Mobius midpoint is weight-scale-invariant). Midpoint epilogue -> yh.
// LDS ~24 KB -> occupancy VGPR-capped at 4 blocks/CU (was 3 LDS-capped).
// ---------------------------------------------------------------------------
__global__ __launch_bounds__(256) void k_attn1(
    const unsigned short* __restrict__ qhh, const unsigned short* __restrict__ qhl,
    const unsigned short* __restrict__ khh, const unsigned short* __restrict__ khl,
    const unsigned short* __restrict__ vth, const unsigned short* __restrict__ vtl,
    const float* __restrict__ q2n, const float* __restrict__ k2n,
    const float* __restrict__ lam1, const float* __restrict__ scale_p,
    float* __restrict__ attn, float* __restrict__ rowsum,
    float* __restrict__ yh) {
  __shared__ __align__(16) unsigned short kldsh[32 * 72];
  __shared__ __align__(16) unsigned short kldsl[32 * 72];
  __shared__ __align__(16) unsigned short vldsh[64 * 36];
  __shared__ __align__(16) unsigned short vldsl[64 * 36];
  __shared__ __align__(16) unsigned short wlds[4][16 * 36];
  __shared__ __align__(16) float k2s[32];
  __shared__ __align__(16) float l1s[32];
  __shared__ float dred[4][16];
  const int t = threadIdx.x, l = t & 63, w = t >> 6;
  const int lr = l & 15, lg = l >> 4;
  const int bh = blockIdx.y, q0 = blockIdx.x * 64;
  const size_t hbase = (size_t)bh * Ll;
  const float scale = scale_p[0];
  const bool sone = (scale == 1.0f);

  // Q fragments (B operand): col = q = q0 + w*16 + lr, d-slice s*32 + lg*8.
  short8 aqh[2], aql[2];
#pragma unroll
  for (int s = 0; s < 2; s++) {
    const size_t off = (hbase + q0 + w * 16 + lr) * (size_t)DHh + s * 32 + lg * 8;
    aqh[s] = *(const short8*)&qhh[off];
    aql[s] = *(const short8*)&qhl[off];
  }
  const float q2v = q2n[hbase + q0 + w * 16 + lr];

  // staging indices: K chunk 32 rows x 64 d; V^T chunk 64 d x 32 k.
  const int kr = t >> 3, kf = t & 7;
  const int vd = t >> 2, vf = t & 3;

  float rs = 0.0f, dacc = 0.0f;
  f32x4 pv[4] = {};

  for (int c = 0; c < 32; c++) {
    const size_t kg = (hbase + c * 32 + kr) * (size_t)DHh + kf * 8;
    const short8 pkh = *(const short8*)&khh[kg];
    const short8 pkl = *(const short8*)&khl[kg];
    const size_t vg = ((size_t)bh * DHh + vd) * (size_t)Ll + c * 32 + vf * 8;
    const short8 pvh = *(const short8*)&vth[vg];
    const short8 pvl = *(const short8*)&vtl[vg];
    float k2r = 0.0f, l1r = 0.0f;
    if (t < 32) {
      k2r = k2n[hbase + c * 32 + t];
      l1r = lam1[hbase + c * 32 + t];
    }
    __syncthreads();  // prior iteration's LDS reads complete
    *(short8*)&kldsh[kr * 72 + kf * 8] = pkh;
    *(short8*)&kldsl[kr * 72 + kf * 8] = pkl;
    *(short8*)&vldsh[vd * 36 + vf * 8] = pvh;
    *(short8*)&vldsl[vd * 36 + vf * 8] = pvl;
    if (t < 32) {
      k2s[t] = k2r;
      l1s[t] = l1r;
    }
    __syncthreads();  // staging visible

#pragma unroll
    for (int j = 0; j < 2; j++) {
      f32x4 acc = {};
#pragma unroll
      for (int s = 0; s < 2; s++) {
        const int ko = (j * 16 + lr) * 72 + s * 32 + lg * 8;
        const short8 kfh = *(const short8*)&kldsh[ko];
        const short8 kfl = *(const short8*)&kldsl[ko];
        acc = __builtin_amdgcn_mfma_f32_16x16x32_bf16(kfh, aqh[s], acc, 0, 0, 0);
        acc = __builtin_amdgcn_mfma_f32_16x16x32_bf16(kfh, aql[s], acc, 0, 0, 0);
        acc = __builtin_amdgcn_mfma_f32_16x16x32_bf16(kfl, aqh[s], acc, 0, 0, 0);
      }
      const float4 k2q = *(const float4*)&k2s[j * 16 + lg * 4];
      const float4 l1q = *(const float4*)&l1s[j * 16 + lg * 4];
      const float kq[4] = {k2q.x, k2q.y, k2q.z, k2q.w};
      const float lq[4] = {l1q.x, l1q.y, l1q.z, l1q.w};
      float en[4];
      short4v wv;
#pragma unroll
      for (int r = 0; r < 4; r++) {
        const float e = score_e(acc[r], q2v, kq[r], scale, sone);
        en[r] = e;
        rs += e;
        __hip_bfloat16 eb = __float2bfloat16(e);
        wv[r] = *(short*)&eb;
        dacc += __bfloat162float(eb) * lq[r];  // den from SAME rounded w
      }
      *(float4*)&attn[(hbase + q0 + w * 16 + lr) * (size_t)Ll + c * 32 +
                      j * 16 + lg * 4] = make_float4(en[0], en[1], en[2], en[3]);
      *(short4v*)&wlds[w][lr * 36 + j * 16 + lg * 4] = wv;
    }
    // PV: A = w (16q x 32k, hi bf16, wave-local), B = (lam v)^T [d][k].
    {
      const short8 wa = *(const short8*)&wlds[w][lr * 36 + lg * 8];
#pragma unroll
      for (int n = 0; n < 4; n++) {
        const int bo = (n * 16 + lr) * 36 + lg * 8;
        const short8 vbh8 = *(const short8*)&vldsh[bo];
        const short8 vbl8 = *(const short8*)&vldsl[bo];
        pv[n] = __builtin_amdgcn_mfma_f32_16x16x32_bf16(wa, vbh8, pv[n], 0, 0, 0);
        pv[n] = __builtin_amdgcn_mfma_f32_16x16x32_bf16(wa, vbl8, pv[n], 0, 0, 0);
      }
    }
  }

  // rowsum: lane's partial covers (lg, j) k-subsets for q = lr.
  rs += __shfl_xor(rs, 16, 64);
  rs += __shfl_xor(rs, 32, 64);
  if (lg == 0) rowsum[hbase + q0 + w * 16 + lr] = rs;

  dacc += __shfl_xor(dacc, 16, 64);
  dacc += __shfl_xor(dacc, 32, 64);
  if (lg == 0) dred[w][lr] = dacc;  // wave-local redistribute

  const int b = bh / Hh, h = bh % Hh;
#pragma unroll
  for (int r = 0; r < 4; r++) {
    float den = dred[w][lg * 4 + r];
    if (fabsf(den) < 1e-10f) den = 1e-10f;
    const float dinv = 1.0f / den;
    float tm[4];
    float n2 = 0.0f;
#pragma unroll
    for (int n = 0; n < 4; n++) {
      tm[n] = pv[n][r] * dinv;
      n2 += tm[n] * tm[n];
    }
    n2 += __shfl_xor(n2, 1, 64);
    n2 += __shfl_xor(n2, 2, 64);
    n2 += __shfl_xor(n2, 4, 64);
    n2 += __shfl_xor(n2, 8, 64);
    const float nn = sqrtf(fmaxf(n2, EPSf * EPSf));
    const float nc = fminf(nn, MAXN);
    // tanh(artanh(nc)/2) = nc / (1 + sqrt(1 - nc^2))
    const float pn = nc / (1.0f + sqrtf(fmaxf(1.0f - nc * nc, 0.0f)));
    const float f = pn / nn * fminf(1.0f, MAXN / fmaxf(pn, EPSf));
    const int ql = q0 + w * 16 + lg * 4 + r;
#pragma unroll
    for (int n = 0; n < 4; n++)
      yh[(((size_t)(b * Ll + ql)) * Hh + h) * DHh + n * 16 + lr] = f * tm[n];
  }
}

// ---------------------------------------------------------------------------
// Normalize attn rows in place (memory-bound): one row per block.
// ---------------------------------------------------------------------------
__global__ __launch_bounds__(256) void k_norm(float* __restrict__ attn,
                                              const float* __restrict__ rowsum) {
  const int row = blockIdx.x;
  const float rinv = 1.0f / rowsum[row];
  float4* p = (float4*)(attn + (size_t)row * Ll);
  float4 v = p[threadIdx.x];
  v.x *= rinv; v.y *= rinv; v.z *= rinv; v.w *= rinv;
  p[threadIdx.x] = v;
}

// ---------------------------------------------------------------------------
// beta_concat: per-head logmap0 / BETA_RATIO, then expmap0 over full D.
// ---------------------------------------------------------------------------
__global__ __launch_bounds__(768) void k_concat(
    const float* __restrict__ yh, float* __restrict__ yc, float beta_ratio) {
  const int t = threadIdx.x;
  const int row = blockIdx.x;
  const int w = t >> 6, lane = t & 63;
  __shared__ float red[12];
  const float ye = yh[(size_t)row * Dd + t];
  const float hs = wred64(ye * ye);
  const float hn = sqrtf(fmaxf(hs, EPSf * EPSf));
  const float cc = artanh_(fminf(hn, MAXN)) / hn / beta_ratio;
  const float ve = cc * ye;
  const float s = wred64(ve * ve);
  if (lane == 0) red[w] = s;
  __syncthreads();
  float n2 = 0.0f;
#pragma unroll
  for (int i = 0; i < 12; i++) n2 += red[i];
  const float n = sqrtf(fmaxf(n2, EPSf * EPSf));
  const float f = tanhf(n) / n;
  yc[(size_t)row * Dd + t] = f * ve;
}

// ---------------------------------------------------------------------------
// Final: mobius_matvec scaling (project), mobius_add with bias, project.
// ---------------------------------------------------------------------------
__global__ __launch_bounds__(768) void k_final(
    const float* __restrict__ yc, const float* __restrict__ mp,
    const float* __restrict__ bp, float* __restrict__ out) {
  const int t = threadIdx.x;
  const int row = blockIdx.x;
  const int w = t >> 6, lane = t & 63;
  __shared__ float red[12];
  auto blockSum = [&](float v) -> float {
    __syncthreads();
    const float s = wred64(v);
    if (lane == 0) red[w] = s;
    __syncthreads();
    float tot = 0.0f;
#pragma unroll
    for (int i = 0; i < 12; i++) tot += red[i];
    return tot;
  };
  const float xe = yc[(size_t)row * Dd + t];
  const float me = mp[(size_t)row * Dd + t];
  const float be = bp[t];
  const float xn2 = blockSum(xe * xe);
  const float xn = sqrtf(fmaxf(xn2, EPSf * EPSf));
  const float arx = artanh_(fminf(xn, MAXN));
  const float mn2 = blockSum(me * me);
  const float mxn = sqrtf(fmaxf(mn2, EPSf * EPSf));
  const float pn = tanhf(mxn / xn * arx);
  const float c1 = pn / mxn * fminf(1.0f, MAXN / fmaxf(pn, EPSf));
  const float mme = c1 * me;
  const float x2 = blockSum(mme * mme);
  const float y2 = blockSum(be * be);
  const float xy = blockSum(mme * be);
  const float nume = (1.0f + 2.0f * xy + y2) * mme + (1.0f - x2) * be;
  const float den = fmaxf(1.0f + 2.0f * xy + x2 * y2, EPSf);
  const float re = nume / den;
  const float rn2 = blockSum(re * re);
  const float rn = sqrtf(fmaxf(rn2, EPSf * EPSf));
  const float f = fminf(1.0f, MAXN / rn);
  out[(size_t)row * Dd + t] = f * re;
}

}  // namespace

extern "C" void kernel_launch(void* const* d_in, const int* in_sizes, int n_in,
                              void* d_out, int out_size, void* d_ws,
                              size_t ws_size, hipStream_t stream) {
  const float* x = (const float*)d_in[0];
  const float* Wq = (const float*)d_in[1];
  const float* Wk = (const float*)d_in[2];
  const float* Wv = (const float*)d_in[3];
  const float* Wp = (const float*)d_in[4];
  const float* bp = (const float*)d_in[5];
  const float* scale = (const float*)d_in[6];

  float* out = (float*)d_out;
  float* y_out = out;                        // (B,L,D)
  float* attn = out + (size_t)Bb * Ll * Dd;  // (B,H,L,L)

  const size_t NH = (size_t)Bb * Hh * Ll;  // 98304
  const size_t RD = (size_t)Bb * Ll * Dd;  // 6291456

  unsigned short* u = (unsigned short*)d_ws;
  unsigned short* qhh = u;
  unsigned short* qhl = u + RD;
  unsigned short* khh = u + 2 * RD;
  unsigned short* khl = u + 3 * RD;
  unsigned short* vth = u + 4 * RD;
  unsigned short* vtl = u + 5 * RD;
  unsigned short* vhh = u + 6 * RD;  // dead after k_vt
  unsigned short* vhl_ = u + 7 * RD;
  unsigned short* whi = u + 8 * RD;  // 4*DD ushorts
  unsigned short* wlo = whi + 4 * (size_t)DDm;
  float* fb = (float*)(wlo + 4 * (size_t)DDm);
  float* q2n = fb;
  float* k2n = fb + NH;
  float* lam1 = fb + 2 * NH;
  float* rowsum = fb + 3 * NH;
  // overlays (dead-region reuse after k_attn1):
  float* yh = (float*)(u + 6 * RD);   // RD floats over vhh/vhl_
  float* yc = (float*)u;              // RD floats over qhh/qhl
  unsigned short* ychi = u + 2 * RD;  // over khh
  unsigned short* yclo = u + 3 * RD;  // over khl
  float* mp = (float*)(u + 4 * RD);   // RD floats over vth/vtl

  // GEMM outputs + bf16 x staged in the not-yet-written attn region.
  float* mq = attn;
  float* mk = attn + RD;
  float* mv = attn + 2 * RD;
  unsigned short* xhi = (unsigned short*)(attn + 3 * RD);
  unsigned short* xlo = xhi + RD;

  const double br =
      exp(lgamma(DHh / 2.0) + lgamma(0.5) - lgamma(DHh / 2.0 + 0.5) -
          (lgamma(Dd / 2.0) + lgamma(0.5) - lgamma(Dd / 2.0 + 0.5)));
  const float beta_ratio = (float)br;

  (void)in_sizes; (void)n_in; (void)out_size; (void)ws_size;

  k_cvt<<<dim3((int)(RD / 4 / 256)), dim3(256), 0, stream>>>(x, xhi, xlo,
                                                             (int)(RD / 4));
  k_cvt<<<dim3(DDm / 4 / 256), dim3(256), 0, stream>>>(Wq, whi, wlo, DDm / 4);
  k_cvt<<<dim3(DDm / 4 / 256), dim3(256), 0, stream>>>(
      Wk, whi + (size_t)DDm, wlo + (size_t)DDm, DDm / 4);
  k_cvt<<<dim3(DDm / 4 / 256), dim3(256), 0, stream>>>(
      Wv, whi + 2 * (size_t)DDm, wlo + 2 * (size_t)DDm, DDm / 4);
  k_cvt<<<dim3(DDm / 4 / 256), dim3(256), 0, stream>>>(
      Wp, whi + 3 * (size_t)DDm, wlo + 3 * (size_t)DDm, DDm / 4);

  k_gemm_bf16s<<<dim3(Dd / 128, (Bb * Ll) / 128, 3), dim3(256), 0, stream>>>(
      xhi, xlo, whi, wlo, mq);

  k_qkv_transform<<<dim3(Bb * Ll), dim3(768), 0, stream>>>(
      x, mq, mk, mv, qhh, qhl, khh, khl, vhh, vhl_, q2n, k2n, lam1,
      beta_ratio);

  k_vt<<<dim3(16, Bb * Hh), dim3(256), 0, stream>>>(vhh, vhl_, vth, vtl);

  k_attn1<<<dim3(16, Bb * Hh), dim3(256), 0, stream>>>(
      qhh, qhl, khh, khl, vth, vtl, q2n, k2n, lam1, scale, attn, rowsum, yh);

  k_norm<<<dim3((int)NH), dim3(256), 0, stream>>>(attn, rowsum);

  k_concat<<<dim3(Bb * Ll), dim3(768), 0, stream>>>(yh, yc, beta_ratio);

  k_cvt<<<dim3((int)(RD / 4 / 256)), dim3(256), 0, stream>>>(yc, ychi, yclo,
                                                             (int)(RD / 4));
  k_gemm_bf16s<<<dim3(Dd / 128, (Bb * Ll) / 128, 1), dim3(256), 0, stream>>>(
      ychi, yclo, whi + 3 * (size_t)DDm, wlo + 3 * (size_t)DDm, mp);

  k_final<<<dim3(Bb * Ll), dim3(768), 0, stream>>>(yc, mp, bp, y_out);
}

// Round 7
// 757.948 us; speedup vs baseline: 1.2003x; 1.0552x over previous
//
#include <hip/hip_runtime.h>
#include <hip/hip_bf16.h>
#include <math.h>

namespace {

constexpr int Bb = 8, Ll = 1024, Dd = 768, Hh = 12, DHh = 64;
constexpr int DDm = Dd * Dd;
constexpr float MAXN = 1.0f - 1e-5f;
constexpr float EPSf = 1e-15f;

typedef __attribute__((ext_vector_type(8))) short short8;
typedef __attribute__((ext_vector_type(4))) short short4v;
typedef __attribute__((ext_vector_type(4))) float f32x4;

__device__ __forceinline__ float wred64(float v) {
#pragma unroll
  for (int m = 32; m >= 1; m >>= 1) v += __shfl_xor(v, m, 64);
  return v;
}

__device__ __forceinline__ float artanh_(float x) {
  return 0.5f * logf((1.0f + x) / (1.0f - x));
}

__device__ __forceinline__ void bsplit(float x, unsigned short& h,
                                       unsigned short& l) {
  __hip_bfloat16 hb = __float2bfloat16(x);
  const float hf = __bfloat162float(hb);
  __hip_bfloat16 lb = __float2bfloat16(x - hf);
  h = *(unsigned short*)&hb;
  l = *(unsigned short*)&lb;
}

// e = exp(-scale * 2*artanh(t)) = ((1-t)/(1+t))^scale ; fast path scale==1.
__device__ __forceinline__ float score_e(float qk, float q2v, float k2v,
                                         float scale, bool sone) {
  const float s2 = q2v + k2v;
  const float h1 = fmaf(q2v, k2v, 1.0f);
  const float qk2 = qk + qk;
  const float diff2 = fmaxf(s2 - qk2, 0.0f);
  const float den = h1 - qk2;  // > 0.5 for points with norm <= ~0.5
  const float t = fminf(
      diff2 * __builtin_amdgcn_rsqf(fmaxf(diff2 * den, 1e-30f)), MAXN);
  const float p = (1.0f - t) * __builtin_amdgcn_rcpf(1.0f + t);
  return sone ? p : expf(scale * logf(p));
}

// ---------------------------------------------------------------------------
// Split fp32 -> bf16 hi + bf16 lo.
// ---------------------------------------------------------------------------
__global__ __launch_bounds__(256) void k_cvt(const float* __restrict__ in,
                                             unsigned short* __restrict__ hi,
                                             unsigned short* __restrict__ lo,
                                             int n4) {
  const int i = blockIdx.x * 256 + threadIdx.x;
  if (i >= n4) return;
  float4 v = ((const float4*)in)[i];
  float xs[4] = {v.x, v.y, v.z, v.w};
  unsigned short hs[4], ls[4];
#pragma unroll
  for (int j = 0; j < 4; j++) bsplit(xs[j], hs[j], ls[j]);
  ((ushort4*)hi)[i] = make_ushort4(hs[0], hs[1], hs[2], hs[3]);
  ((ushort4*)lo)[i] = make_ushort4(ls[0], ls[1], ls[2], ls[3]);
}

// 4 weight matrices in one launch (blockIdx.z selects source).
__global__ __launch_bounds__(256) void k_cvt4(
    const float* __restrict__ w0, const float* __restrict__ w1,
    const float* __restrict__ w2, const float* __restrict__ w3,
    unsigned short* __restrict__ hi, unsigned short* __restrict__ lo) {
  const int z = blockIdx.z;
  const float* in = (z == 0) ? w0 : (z == 1) ? w1 : (z == 2) ? w2 : w3;
  const int i = blockIdx.x * 256 + threadIdx.x;
  if (i >= DDm / 4) return;
  float4 v = ((const float4*)in)[i];
  float xs[4] = {v.x, v.y, v.z, v.w};
  unsigned short hs[4], ls[4];
#pragma unroll
  for (int j = 0; j < 4; j++) bsplit(xs[j], hs[j], ls[j]);
  ((ushort4*)(hi + (size_t)z * DDm))[i] = make_ushort4(hs[0], hs[1], hs[2], hs[3]);
  ((ushort4*)(lo + (size_t)z * DDm))[i] = make_ushort4(ls[0], ls[1], ls[2], ls[3]);
}

// ---------------------------------------------------------------------------
// bf16-split MFMA GEMM: C = A @ W^T (~fp32 precision), software-pipelined:
// chunk c+1 global loads issued right after barrier B, hidden under chunk c
// compute.
// ---------------------------------------------------------------------------
__global__ __launch_bounds__(256) void k_gemm_bf16s(
    const unsigned short* __restrict__ Ahi, const unsigned short* __restrict__ Alo,
    const unsigned short* __restrict__ Whi, const unsigned short* __restrict__ Wlo,
    float* __restrict__ C) {
  constexpr int K = Dd, N = Dd;
  const int z = blockIdx.z;
  const unsigned short* Bh = Whi + (size_t)z * DDm;
  const unsigned short* Bl = Wlo + (size_t)z * DDm;
  float* Cz = C + (size_t)z * 8192 * N;
  __shared__ __align__(16) unsigned short sAh[128 * 32];
  __shared__ __align__(16) unsigned short sAl[128 * 32];
  __shared__ __align__(16) unsigned short sBh[128 * 32];
  __shared__ __align__(16) unsigned short sBl[128 * 32];
  const int t = threadIdx.x;
  const int l = t & 63, wid = t >> 6;
  const int wr = wid >> 1, wc = wid & 1;
  const int m0 = blockIdx.y * 128, n0 = blockIdx.x * 128;

  const int r0 = t >> 2, kf0 = t & 3;
  const int r1 = (t + 256) >> 2, kf1 = (t + 256) & 3;
  const int sw0 = r0 * 32 + ((kf0 ^ ((r0 >> 1) & 3)) << 3);
  const int sw1 = r1 * 32 + ((kf1 ^ ((r1 >> 1) & 3)) << 3);
  const size_t ga0 = (size_t)(m0 + r0) * K + kf0 * 8;
  const size_t ga1 = (size_t)(m0 + r1) * K + kf1 * 8;
  const size_t gb0 = (size_t)(n0 + r0) * K + kf0 * 8;
  const size_t gb1 = (size_t)(n0 + r1) * K + kf1 * 8;

  const int lar = l & 15, lkf = l >> 4;

  f32x4 acc[4][4] = {};

  short8 vah0, vah1, val0, val1, vbh0, vbh1, vbl0, vbl1;
  auto load_chunk = [&](int k0) {
    vah0 = *(const short8*)&Ahi[ga0 + k0];
    vah1 = *(const short8*)&Ahi[ga1 + k0];
    val0 = *(const short8*)&Alo[ga0 + k0];
    val1 = *(const short8*)&Alo[ga1 + k0];
    vbh0 = *(const short8*)&Bh[gb0 + k0];
    vbh1 = *(const short8*)&Bh[gb1 + k0];
    vbl0 = *(const short8*)&Bl[gb0 + k0];
    vbl1 = *(const short8*)&Bl[gb1 + k0];
  };
  load_chunk(0);

  for (int k0 = 0; k0 < K; k0 += 32) {
    __syncthreads();  // prior iteration's LDS reads complete
    *(short8*)&sAh[sw0] = vah0;
    *(short8*)&sAh[sw1] = vah1;
    *(short8*)&sAl[sw0] = val0;
    *(short8*)&sAl[sw1] = val1;
    *(short8*)&sBh[sw0] = vbh0;
    *(short8*)&sBh[sw1] = vbh1;
    *(short8*)&sBl[sw0] = vbl0;
    *(short8*)&sBl[sw1] = vbl1;
    __syncthreads();  // staging visible
    if (k0 + 32 < K) load_chunk(k0 + 32);  // prefetch: hides under compute

    short8 ah[4], al[4], bh[4], bl[4];
#pragma unroll
    for (int f = 0; f < 4; f++) {
      const int ra = wr * 64 + f * 16 + lar;
      const int ia = ra * 32 + ((lkf ^ ((ra >> 1) & 3)) << 3);
      ah[f] = *(const short8*)&sAh[ia];
      al[f] = *(const short8*)&sAl[ia];
      const int rb = wc * 64 + f * 16 + lar;
      const int ib = rb * 32 + ((lkf ^ ((rb >> 1) & 3)) << 3);
      bh[f] = *(const short8*)&sBh[ib];
      bl[f] = *(const short8*)&sBl[ib];
    }
#pragma unroll
    for (int i = 0; i < 4; i++)
#pragma unroll
      for (int j = 0; j < 4; j++) {
        acc[i][j] = __builtin_amdgcn_mfma_f32_16x16x32_bf16(ah[i], bh[j],
                                                            acc[i][j], 0, 0, 0);
        acc[i][j] = __builtin_amdgcn_mfma_f32_16x16x32_bf16(ah[i], bl[j],
                                                            acc[i][j], 0, 0, 0);
        acc[i][j] = __builtin_amdgcn_mfma_f32_16x16x32_bf16(al[i], bh[j],
                                                            acc[i][j], 0, 0, 0);
      }
  }

#pragma unroll
  for (int i = 0; i < 4; i++)
#pragma unroll
    for (int j = 0; j < 4; j++) {
      const int row = m0 + wr * 64 + i * 16 + (l >> 4) * 4;
      const int col = n0 + wc * 64 + j * 16 + (l & 15);
      const f32x4 v = acc[i][j];
#pragma unroll
      for (int q = 0; q < 4; q++) Cz[(size_t)(row + q) * N + col] = v[q];
    }
}

// ---------------------------------------------------------------------------
// Per-row transform; emits q/k/(lam*v) as bf16 hi/lo + per-head stats.
// ---------------------------------------------------------------------------
__global__ __launch_bounds__(768) void k_qkv_transform(
    const float* __restrict__ x,
    const float* __restrict__ mq, const float* __restrict__ mk,
    const float* __restrict__ mv,
    unsigned short* __restrict__ qhh, unsigned short* __restrict__ qhl,
    unsigned short* __restrict__ khh, unsigned short* __restrict__ khl,
    unsigned short* __restrict__ vhh, unsigned short* __restrict__ vhl_,
    float* __restrict__ q2n, float* __restrict__ k2n,
    float* __restrict__ lam1, float beta_ratio) {
  const int t = threadIdx.x;
  const int row = blockIdx.x;  // b*L + l
  const int b = row >> 10, l = row & 1023;
  const int w = t >> 6, lane = t & 63;
  __shared__ float red[12];

  const float xe = x[(size_t)row * Dd + t];
  float s = wred64(xe * xe);
  if (lane == 0) red[w] = s;
  __syncthreads();
  float xn2 = 0.0f;
#pragma unroll
  for (int i = 0; i < 12; i++) xn2 += red[i];
  const float xn = sqrtf(fmaxf(xn2, EPSf * EPSf));
  const float arx = artanh_(fminf(xn, MAXN));

  const float* mptr[3] = {mq, mk, mv};
#pragma unroll
  for (int mi = 0; mi < 3; mi++) {
    const float me = mptr[mi][(size_t)row * Dd + t];
    __syncthreads();
    float s2 = wred64(me * me);
    if (lane == 0) red[w] = s2;
    __syncthreads();
    float mn2 = 0.0f;
#pragma unroll
    for (int i = 0; i < 12; i++) mn2 += red[i];
    const float mxn = sqrtf(fmaxf(mn2, EPSf * EPSf));
    const float pn = tanhf(mxn / xn * arx);
    const float c1 = pn / mxn * fminf(1.0f, MAXN / fmaxf(pn, EPSf));
    const float nn = fmaxf(fminf(pn, MAXN), EPSf);
    const float c2 = artanh_(nn) / nn;
    const float ve = c2 * c1 * me * beta_ratio;
    const float hs = wred64(ve * ve);
    const float hn = sqrtf(fmaxf(hs, EPSf * EPSf));
    const float th = tanhf(hn);
    const float oe = th / hn * ve;
    const size_t hidx = (size_t)(b * Hh + w) * Ll + l;
    const size_t oidx = hidx * DHh + lane;
    unsigned short hu, lu;
    if (mi == 0) {
      bsplit(oe, hu, lu);
      qhh[oidx] = hu; qhl[oidx] = lu;
      if (lane == 0) q2n[hidx] = th * th;
    } else if (mi == 1) {
      bsplit(oe, hu, lu);
      khh[oidx] = hu; khl[oidx] = lu;
      if (lane == 0) k2n[hidx] = th * th;
    } else {
      const float lam = 2.0f / fmaxf(1.0f - th * th, EPSf);
      bsplit(lam * oe, hu, lu);
      vhh[oidx] = hu; vhl_[oidx] = lu;
      if (lane == 0) lam1[hidx] = lam - 1.0f;
    }
  }
}

// ---------------------------------------------------------------------------
// Transpose lam*v per head: [k][d] -> [d][k] (bf16 hi/lo).
// ---------------------------------------------------------------------------
__global__ __launch_bounds__(256) void k_vt(const unsigned short* __restrict__ vh,
                                            const unsigned short* __restrict__ vl,
                                            unsigned short* __restrict__ th,
                                            unsigned short* __restrict__ tl) {
  __shared__ __align__(16) unsigned short sh[64 * 72];
  __shared__ __align__(16) unsigned short sl[64 * 72];
  const int t = threadIdx.x;
  const int bh = blockIdx.y, c = blockIdx.x;
  const size_t ibase = ((size_t)bh * Ll + c * 64) * DHh;
#pragma unroll
  for (int u = 0; u < 2; u++) {
    const int ch = t + u * 256, r = ch >> 3, f = ch & 7;
    *(short8*)&sh[r * 72 + f * 8] = *(const short8*)&vh[ibase + r * DHh + f * 8];
    *(short8*)&sl[r * 72 + f * 8] = *(const short8*)&vl[ibase + r * DHh + f * 8];
  }
  __syncthreads();
#pragma unroll
  for (int u = 0; u < 2; u++) {
    const int ch = t + u * 256, d = ch >> 3, kb = ch & 7;
    short8 oh, ol;
#pragma unroll
    for (int i = 0; i < 8; i++) {
      oh[i] = (short)sh[(kb * 8 + i) * 72 + d];
      ol[i] = (short)sl[(kb * 8 + i) * 72 + d];
    }
    const size_t ob = ((size_t)bh * DHh + d) * Ll + c * 64 + kb * 8;
    *(short8*)&th[ob] = oh;
    *(short8*)&tl[ob] = ol;
  }
}

// ---------------------------------------------------------------------------
// Fused attention, SINGLE pass, software-pipelined (chunk c+1 loads issued
// after barrier B of chunk c). Grid (16, B*H), 256 threads (4 waves).
// Writes UNNORMALIZED e (fp32) + rowsums; k_norm normalizes afterwards.
// PV/den use unnormalized bf16 weights (midpoint is scale-invariant).
// ---------------------------------------------------------------------------
__global__ __launch_bounds__(256) void k_attn1(
    const unsigned short* __restrict__ qhh, const unsigned short* __restrict__ qhl,
    const unsigned short* __restrict__ khh, const unsigned short* __restrict__ khl,
    const unsigned short* __restrict__ vth, const unsigned short* __restrict__ vtl,
    const float* __restrict__ q2n, const float* __restrict__ k2n,
    const float* __restrict__ lam1, const float* __restrict__ scale_p,
    float* __restrict__ attn, float* __restrict__ rowsum,
    float* __restrict__ yh) {
  __shared__ __align__(16) unsigned short kldsh[32 * 72];
  __shared__ __align__(16) unsigned short kldsl[32 * 72];
  __shared__ __align__(16) unsigned short vldsh[64 * 36];
  __shared__ __align__(16) unsigned short vldsl[64 * 36];
  __shared__ __align__(16) unsigned short wlds[4][16 * 36];
  __shared__ __align__(16) float k2s[32];
  __shared__ __align__(16) float l1s[32];
  __shared__ float dred[4][16];
  const int t = threadIdx.x, l = t & 63, w = t >> 6;
  const int lr = l & 15, lg = l >> 4;
  const int bh = blockIdx.y, q0 = blockIdx.x * 64;
  const size_t hbase = (size_t)bh * Ll;
  const float scale = scale_p[0];
  const bool sone = (scale == 1.0f);

  short8 aqh[2], aql[2];
#pragma unroll
  for (int s = 0; s < 2; s++) {
    const size_t off = (hbase + q0 + w * 16 + lr) * (size_t)DHh + s * 32 + lg * 8;
    aqh[s] = *(const short8*)&qhh[off];
    aql[s] = *(const short8*)&qhl[off];
  }
  const float q2v = q2n[hbase + q0 + w * 16 + lr];

  const int kr = t >> 3, kf = t & 7;
  const int vd = t >> 2, vf = t & 3;

  float rs = 0.0f, dacc = 0.0f;
  f32x4 pv[4] = {};

  short8 pkh, pkl, pvh, pvl;
  float k2r = 0.0f, l1r = 0.0f;
  auto load_chunk = [&](int c) {
    const size_t kg = (hbase + c * 32 + kr) * (size_t)DHh + kf * 8;
    pkh = *(const short8*)&khh[kg];
    pkl = *(const short8*)&khl[kg];
    const size_t vg = ((size_t)bh * DHh + vd) * (size_t)Ll + c * 32 + vf * 8;
    pvh = *(const short8*)&vth[vg];
    pvl = *(const short8*)&vtl[vg];
    if (t < 32) {
      k2r = k2n[hbase + c * 32 + t];
      l1r = lam1[hbase + c * 32 + t];
    }
  };
  load_chunk(0);

  for (int c = 0; c < 32; c++) {
    __syncthreads();  // prior iteration's LDS reads complete
    *(short8*)&kldsh[kr * 72 + kf * 8] = pkh;
    *(short8*)&kldsl[kr * 72 + kf * 8] = pkl;
    *(short8*)&vldsh[vd * 36 + vf * 8] = pvh;
    *(short8*)&vldsl[vd * 36 + vf * 8] = pvl;
    if (t < 32) {
      k2s[t] = k2r;
      l1s[t] = l1r;
    }
    __syncthreads();  // staging visible
    if (c + 1 < 32) load_chunk(c + 1);  // prefetch: hides under compute

#pragma unroll
    for (int j = 0; j < 2; j++) {
      f32x4 acc = {};
#pragma unroll
      for (int s = 0; s < 2; s++) {
        const int ko = (j * 16 + lr) * 72 + s * 32 + lg * 8;
        const short8 kfh = *(const short8*)&kldsh[ko];
        const short8 kfl = *(const short8*)&kldsl[ko];
        acc = __builtin_amdgcn_mfma_f32_16x16x32_bf16(kfh, aqh[s], acc, 0, 0, 0);
        acc = __builtin_amdgcn_mfma_f32_16x16x32_bf16(kfh, aql[s], acc, 0, 0, 0);
        acc = __builtin_amdgcn_mfma_f32_16x16x32_bf16(kfl, aqh[s], acc, 0, 0, 0);
      }
      const float4 k2q = *(const float4*)&k2s[j * 16 + lg * 4];
      const float4 l1q = *(const float4*)&l1s[j * 16 + lg * 4];
      const float kq[4] = {k2q.x, k2q.y, k2q.z, k2q.w};
      const float lq[4] = {l1q.x, l1q.y, l1q.z, l1q.w};
      float en[4];
      short4v wv;
#pragma unroll
      for (int r = 0; r < 4; r++) {
        const float e = score_e(acc[r], q2v, kq[r], scale, sone);
        en[r] = e;
        rs += e;
        __hip_bfloat16 eb = __float2bfloat16(e);
        wv[r] = *(short*)&eb;
        dacc += __bfloat162float(eb) * lq[r];  // den from SAME rounded w
      }
      *(float4*)&attn[(hbase + q0 + w * 16 + lr) * (size_t)Ll + c * 32 +
                      j * 16 + lg * 4] = make_float4(en[0], en[1], en[2], en[3]);
      *(short4v*)&wlds[w][lr * 36 + j * 16 + lg * 4] = wv;
    }
    // PV: A = w (16q x 32k, hi bf16, wave-local), B = (lam v)^T [d][k].
    {
      const short8 wa = *(const short8*)&wlds[w][lr * 36 + lg * 8];
#pragma unroll
      for (int n = 0; n < 4; n++) {
        const int bo = (n * 16 + lr) * 36 + lg * 8;
        const short8 vbh8 = *(const short8*)&vldsh[bo];
        const short8 vbl8 = *(const short8*)&vldsl[bo];
        pv[n] = __builtin_amdgcn_mfma_f32_16x16x32_bf16(wa, vbh8, pv[n], 0, 0, 0);
        pv[n] = __builtin_amdgcn_mfma_f32_16x16x32_bf16(wa, vbl8, pv[n], 0, 0, 0);
      }
    }
  }

  rs += __shfl_xor(rs, 16, 64);
  rs += __shfl_xor(rs, 32, 64);
  if (lg == 0) rowsum[hbase + q0 + w * 16 + lr] = rs;

  dacc += __shfl_xor(dacc, 16, 64);
  dacc += __shfl_xor(dacc, 32, 64);
  if (lg == 0) dred[w][lr] = dacc;

  const int b = bh / Hh, h = bh % Hh;
#pragma unroll
  for (int r = 0; r < 4; r++) {
    float den = dred[w][lg * 4 + r];
    if (fabsf(den) < 1e-10f) den = 1e-10f;
    const float dinv = 1.0f / den;
    float tm[4];
    float n2 = 0.0f;
#pragma unroll
    for (int n = 0; n < 4; n++) {
      tm[n] = pv[n][r] * dinv;
      n2 += tm[n] * tm[n];
    }
    n2 += __shfl_xor(n2, 1, 64);
    n2 += __shfl_xor(n2, 2, 64);
    n2 += __shfl_xor(n2, 4, 64);
    n2 += __shfl_xor(n2, 8, 64);
    const float nn = sqrtf(fmaxf(n2, EPSf * EPSf));
    const float nc = fminf(nn, MAXN);
    const float pn = nc / (1.0f + sqrtf(fmaxf(1.0f - nc * nc, 0.0f)));
    const float f = pn / nn * fminf(1.0f, MAXN / fmaxf(pn, EPSf));
    const int ql = q0 + w * 16 + lg * 4 + r;
#pragma unroll
    for (int n = 0; n < 4; n++)
      yh[(((size_t)(b * Ll + ql)) * Hh + h) * DHh + n * 16 + lr] = f * tm[n];
  }
}

// ---------------------------------------------------------------------------
// Normalize attn rows in place (memory-bound): one row per block.
// ---------------------------------------------------------------------------
__global__ __launch_bounds__(256) void k_norm(float* __restrict__ attn,
                                              const float* __restrict__ rowsum) {
  const int row = blockIdx.x;
  const float rinv = 1.0f / rowsum[row];
  float4* p = (float4*)(attn + (size_t)row * Ll);
  float4 v = p[threadIdx.x];
  v.x *= rinv; v.y *= rinv; v.z *= rinv; v.w *= rinv;
  p[threadIdx.x] = v;
}

// ---------------------------------------------------------------------------
// beta_concat: per-head logmap0 / BETA_RATIO, then expmap0 over full D.
// ---------------------------------------------------------------------------
__global__ __launch_bounds__(768) void k_concat(
    const float* __restrict__ yh, float* __restrict__ yc, float beta_ratio) {
  const int t = threadIdx.x;
  const int row = blockIdx.x;
  const int w = t >> 6, lane = t & 63;
  __shared__ float red[12];
  const float ye = yh[(size_t)row * Dd + t];
  const float hs = wred64(ye * ye);
  const float hn = sqrtf(fmaxf(hs, EPSf * EPSf));
  const float cc = artanh_(fminf(hn, MAXN)) / hn / beta_ratio;
  const float ve = cc * ye;
  const float s = wred64(ve * ve);
  if (lane == 0) red[w] = s;
  __syncthreads();
  float n2 = 0.0f;
#pragma unroll
  for (int i = 0; i < 12; i++) n2 += red[i];
  const float n = sqrtf(fmaxf(n2, EPSf * EPSf));
  const float f = tanhf(n) / n;
  yc[(size_t)row * Dd + t] = f * ve;
}

// ---------------------------------------------------------------------------
// Final: mobius_matvec scaling (project), mobius_add with bias, project.
// ---------------------------------------------------------------------------
__global__ __launch_bounds__(768) void k_final(
    const float* __restrict__ yc, const float* __restrict__ mp,
    const float* __restrict__ bp, float* __restrict__ out) {
  const int t = threadIdx.x;
  const int row = blockIdx.x;
  const int w = t >> 6, lane = t & 63;
  __shared__ float red[12];
  auto blockSum = [&](float v) -> float {
    __syncthreads();
    const float s = wred64(v);
    if (lane == 0) red[w] = s;
    __syncthreads();
    float tot = 0.0f;
#pragma unroll
    for (int i = 0; i < 12; i++) tot += red[i];
    return tot;
  };
  const float xe = yc[(size_t)row * Dd + t];
  const float me = mp[(size_t)row * Dd + t];
  const float be = bp[t];
  const float xn2 = blockSum(xe * xe);
  const float xn = sqrtf(fmaxf(xn2, EPSf * EPSf));
  const float arx = artanh_(fminf(xn, MAXN));
  const float mn2 = blockSum(me * me);
  const float mxn = sqrtf(fmaxf(mn2, EPSf * EPSf));
  const float pn = tanhf(mxn / xn * arx);
  const float c1 = pn / mxn * fminf(1.0f, MAXN / fmaxf(pn, EPSf));
  const float mme = c1 * me;
  const float x2 = blockSum(mme * mme);
  const float y2 = blockSum(be * be);
  const float xy = blockSum(mme * be);
  const float nume = (1.0f + 2.0f * xy + y2) * mme + (1.0f - x2) * be;
  const float den = fmaxf(1.0f + 2.0f * xy + x2 * y2, EPSf);
  const float re = nume / den;
  const float rn2 = blockSum(re * re);
  const float rn = sqrtf(fmaxf(rn2, EPSf * EPSf));
  const float f = fminf(1.0f, MAXN / rn);
  out[(size_t)row * Dd + t] = f * re;
}

}  // namespace

extern "C" void kernel_launch(void* const* d_in, const int* in_sizes, int n_in,
                              void* d_out, int out_size, void* d_ws,
                              size_t ws_size, hipStream_t stream) {
  const float* x = (const float*)d_in[0];
  const float* Wq = (const float*)d_in[1];
  const float* Wk = (const float*)d_in[2];
  const float* Wv = (const float*)d_in[3];
  const float* Wp = (const float*)d_in[4];
  const float* bp = (const float*)d_in[5];
  const float* scale = (const float*)d_in[6];

  float* out = (float*)d_out;
  float* y_out = out;                        // (B,L,D)
  float* attn = out + (size_t)Bb * Ll * Dd;  // (B,H,L,L)

  const size_t NH = (size_t)Bb * Hh * Ll;  // 98304
  const size_t RD = (size_t)Bb * Ll * Dd;  // 6291456

  unsigned short* u = (unsigned short*)d_ws;
  unsigned short* qhh = u;
  unsigned short* qhl = u + RD;
  unsigned short* khh = u + 2 * RD;
  unsigned short* khl = u + 3 * RD;
  unsigned short* vth = u + 4 * RD;
  unsigned short* vtl = u + 5 * RD;
  unsigned short* vhh = u + 6 * RD;  // dead after k_vt
  unsigned short* vhl_ = u + 7 * RD;
  unsigned short* whi = u + 8 * RD;  // 4*DD ushorts
  unsigned short* wlo = whi + 4 * (size_t)DDm;
  float* fb = (float*)(wlo + 4 * (size_t)DDm);
  float* q2n = fb;
  float* k2n = fb + NH;
  float* lam1 = fb + 2 * NH;
  float* rowsum = fb + 3 * NH;
  // overlays (dead-region reuse after k_attn1):
  float* yh = (float*)(u + 6 * RD);   // RD floats over vhh/vhl_
  float* yc = (float*)u;              // RD floats over qhh/qhl
  unsigned short* ychi = u + 2 * RD;  // over khh
  unsigned short* yclo = u + 3 * RD;  // over khl
  float* mp = (float*)(u + 4 * RD);   // RD floats over vth/vtl

  // GEMM outputs + bf16 x staged in the not-yet-written attn region.
  float* mq = attn;
  float* mk = attn + RD;
  float* mv = attn + 2 * RD;
  unsigned short* xhi = (unsigned short*)(attn + 3 * RD);
  unsigned short* xlo = xhi + RD;

  const double br =
      exp(lgamma(DHh / 2.0) + lgamma(0.5) - lgamma(DHh / 2.0 + 0.5) -
          (lgamma(Dd / 2.0) + lgamma(0.5) - lgamma(Dd / 2.0 + 0.5)));
  const float beta_ratio = (float)br;

  (void)in_sizes; (void)n_in; (void)out_size; (void)ws_size;

  k_cvt<<<dim3((int)(RD / 4 / 256)), dim3(256), 0, stream>>>(x, xhi, xlo,
                                                             (int)(RD / 4));
  k_cvt4<<<dim3(DDm / 4 / 256, 1, 4), dim3(256), 0, stream>>>(Wq, Wk, Wv, Wp,
                                                              whi, wlo);

  k_gemm_bf16s<<<dim3(Dd / 128, (Bb * Ll) / 128, 3), dim3(256), 0, stream>>>(
      xhi, xlo, whi, wlo, mq);

  k_qkv_transform<<<dim3(Bb * Ll), dim3(768), 0, stream>>>(
      x, mq, mk, mv, qhh, qhl, khh, khl, vhh, vhl_, q2n, k2n, lam1,
      beta_ratio);

  k_vt<<<dim3(16, Bb * Hh), dim3(256), 0, stream>>>(vhh, vhl_, vth, vtl);

  k_attn1<<<dim3(16, Bb * Hh), dim3(256), 0, stream>>>(
      qhh, qhl, khh, khl, vth, vtl, q2n, k2n, lam1, scale, attn, rowsum, yh);

  k_norm<<<dim3((int)NH), dim3(256), 0, stream>>>(attn, rowsum);

  k_concat<<<dim3(Bb * Ll), dim3(768), 0, stream>>>(yh, yc, beta_ratio);

  k_cvt<<<dim3((int)(RD / 4 / 256)), dim3(256), 0, stream>>>(yc, ychi, yclo,
                                                             (int)(RD / 4));
  k_gemm_bf16s<<<dim3(Dd / 128, (Bb * Ll) / 128, 1), dim3(256), 0, stream>>>(
      ychi, yclo, whi + 3 * (size_t)DDm, wlo + 3 * (size_t)DDm, mp);

  k_final<<<dim3(Bb * Ll), dim3(768), 0, stream>>>(yc, mp, bp, y_out);
}